// Round 2
// baseline (2969.391 us; speedup 1.0000x reference)
//
#include <hip/hip_runtime.h>
#include <math.h>

#define D_MODEL 1024
#define D_INNER 2048
#define D_STATE 16
#define DT_RANK 64
#define D_CONV 4
#define BSZ 2
#define SEQ 2048
#define NTOK (BSZ*SEQ)   // 4096
#define EPS 1e-5f

__device__ __forceinline__ float sgnf(float w) {
    return (w > 0.f) ? 1.f : ((w < 0.f) ? -1.f : 0.f);
}

// ----------------------------- LayerNorm ------------------------------------
// one block per row (1024 elems), 256 threads x float4
__global__ __launch_bounds__(256) void ln_kernel(const float* __restrict__ x,
                                                 const float* __restrict__ g,
                                                 const float* __restrict__ b,
                                                 float* __restrict__ out) {
    int row = blockIdx.x, tid = threadIdx.x;
    float4 v = reinterpret_cast<const float4*>(x + (size_t)row * D_MODEL)[tid];
    float s = v.x + v.y + v.z + v.w;
    float q = v.x*v.x + v.y*v.y + v.z*v.z + v.w*v.w;
    #pragma unroll
    for (int off = 32; off > 0; off >>= 1) {
        s += __shfl_down(s, off);
        q += __shfl_down(q, off);
    }
    __shared__ float rs[4], rq[4], smean, srstd;
    if ((tid & 63) == 0) { rs[tid >> 6] = s; rq[tid >> 6] = q; }
    __syncthreads();
    if (tid == 0) {
        float ts = rs[0] + rs[1] + rs[2] + rs[3];
        float tq = rq[0] + rq[1] + rq[2] + rq[3];
        float mean = ts * (1.0f / D_MODEL);
        float var = tq * (1.0f / D_MODEL) - mean * mean;
        smean = mean;
        srstd = rsqrtf(var + EPS);
    }
    __syncthreads();
    float mean = smean, rstd = srstd;
    float4 gg = reinterpret_cast<const float4*>(g)[tid];
    float4 bb = reinterpret_cast<const float4*>(b)[tid];
    float4 o;
    o.x = (v.x - mean) * rstd * gg.x + bb.x;
    o.y = (v.y - mean) * rstd * gg.y + bb.y;
    o.z = (v.z - mean) * rstd * gg.z + bb.z;
    o.w = (v.w - mean) * rstd * gg.w + bb.w;
    reinterpret_cast<float4*>(out + (size_t)row * D_MODEL)[tid] = o;
}

// ----------------------------- GEMM -----------------------------------------
// C[M,N] = A[M,K] (row stride sA) @ W[N,K]^T  (+ epilogue)
// EP: 0 none | 1 +bias,clip[-1,1] | 2 +bias+addx | 3 softplus(acc+bias) | 4 +addx
#define BMT 128
#define BNT 128
#define BKT 16
#define LDT (BMT + 8)

template<int EP, bool SIGNW>
__global__ __launch_bounds__(256) void gemm_kernel(
    const float* __restrict__ A, const float* __restrict__ W, float* __restrict__ C,
    int M, int N, int K, int sA, int sC,
    const float* __restrict__ bias, const float* __restrict__ addx, int sAdd)
{
    __shared__ float As[BKT][LDT];
    __shared__ float Ws[BKT][LDT];
    int tid = threadIdx.x;
    int row0 = blockIdx.y * BMT, col0 = blockIdx.x * BNT;
    int tx = tid & 15, ty = tid >> 4;       // 16x16 thread grid, 8x8 each
    int lr = tid >> 1;                       // 0..127
    int lc = (tid & 1) * 8;                  // 0 or 8
    float acc[8][8] = {};

    for (int k0 = 0; k0 < K; k0 += BKT) {
        {
            int gr = row0 + lr;
            float4 v0 = {0,0,0,0}, v1 = {0,0,0,0};
            if (gr < M) {
                const float* p = A + (size_t)gr * sA + k0 + lc;
                v0 = *reinterpret_cast<const float4*>(p);
                v1 = *reinterpret_cast<const float4*>(p + 4);
            }
            As[lc+0][lr] = v0.x; As[lc+1][lr] = v0.y; As[lc+2][lr] = v0.z; As[lc+3][lr] = v0.w;
            As[lc+4][lr] = v1.x; As[lc+5][lr] = v1.y; As[lc+6][lr] = v1.z; As[lc+7][lr] = v1.w;
        }
        {
            int gn = col0 + lr;
            float4 v0 = {0,0,0,0}, v1 = {0,0,0,0};
            if (gn < N) {
                const float* p = W + (size_t)gn * K + k0 + lc;
                v0 = *reinterpret_cast<const float4*>(p);
                v1 = *reinterpret_cast<const float4*>(p + 4);
            }
            if (SIGNW) {
                v0.x = sgnf(v0.x); v0.y = sgnf(v0.y); v0.z = sgnf(v0.z); v0.w = sgnf(v0.w);
                v1.x = sgnf(v1.x); v1.y = sgnf(v1.y); v1.z = sgnf(v1.z); v1.w = sgnf(v1.w);
            }
            Ws[lc+0][lr] = v0.x; Ws[lc+1][lr] = v0.y; Ws[lc+2][lr] = v0.z; Ws[lc+3][lr] = v0.w;
            Ws[lc+4][lr] = v1.x; Ws[lc+5][lr] = v1.y; Ws[lc+6][lr] = v1.z; Ws[lc+7][lr] = v1.w;
        }
        __syncthreads();
        #pragma unroll
        for (int k = 0; k < BKT; ++k) {
            float4 a0 = *reinterpret_cast<const float4*>(&As[k][ty*8]);
            float4 a1 = *reinterpret_cast<const float4*>(&As[k][ty*8+4]);
            float4 w0 = *reinterpret_cast<const float4*>(&Ws[k][tx*8]);
            float4 w1 = *reinterpret_cast<const float4*>(&Ws[k][tx*8+4]);
            float av[8] = {a0.x,a0.y,a0.z,a0.w,a1.x,a1.y,a1.z,a1.w};
            float wv[8] = {w0.x,w0.y,w0.z,w0.w,w1.x,w1.y,w1.z,w1.w};
            #pragma unroll
            for (int i = 0; i < 8; ++i)
                #pragma unroll
                for (int j = 0; j < 8; ++j)
                    acc[i][j] += av[i] * wv[j];
        }
        __syncthreads();
    }

    #pragma unroll
    for (int i = 0; i < 8; ++i) {
        int gr = row0 + ty*8 + i;
        if (gr >= M) continue;
        #pragma unroll
        for (int j = 0; j < 8; ++j) {
            int gc = col0 + tx*8 + j;
            if (gc >= N) continue;
            float v = acc[i][j];
            if (EP == 1) { v += bias[gc]; v = fminf(1.0f, fmaxf(-1.0f, v)); }
            else if (EP == 2) { v += bias[gc] + addx[(size_t)gr*sAdd + gc]; }
            else if (EP == 3) { float t = v + bias[gc]; v = fmaxf(t, 0.0f) + log1pf(__expf(-fabsf(t))); }
            else if (EP == 4) { v += addx[(size_t)gr*sAdd + gc]; }
            C[(size_t)gr*sC + gc] = v;
        }
    }
}

// ----------------------------- groupwise abs-max + quant --------------------
__global__ __launch_bounds__(64) void init_gamma_kernel(unsigned int* g) {
    if (threadIdx.x < 4) g[threadIdx.x] = 0u;
}

__global__ __launch_bounds__(256) void absmax_kernel(const float* __restrict__ x2,
                                                     unsigned int* __restrict__ gamma_bits) {
    int m = blockIdx.x, tid = threadIdx.x;
    float4 v = reinterpret_cast<const float4*>(x2 + (size_t)m * D_MODEL)[tid];
    float mx = fmaxf(fmaxf(fabsf(v.x), fabsf(v.y)), fmaxf(fabsf(v.z), fabsf(v.w)));
    #pragma unroll
    for (int off = 32; off > 0; off >>= 1) mx = fmaxf(mx, __shfl_down(mx, off));
    __shared__ float red[4];
    if ((tid & 63) == 0) red[tid >> 6] = mx;
    __syncthreads();
    if (tid == 0) {
        float t = fmaxf(fmaxf(red[0], red[1]), fmaxf(red[2], red[3]));
        int g = (m & (SEQ - 1)) >> 9;   // group of 512 seq positions
        atomicMax(gamma_bits + g, __float_as_uint(t));
    }
}

__global__ __launch_bounds__(256) void quant_kernel(const float* __restrict__ x2,
                                                    const unsigned int* __restrict__ gamma_bits,
                                                    float* __restrict__ qx) {
    int idx = blockIdx.x * 256 + threadIdx.x;       // one float4 each
    int m = idx >> 8;                                // 256 float4 per row
    int g = (m & (SEQ - 1)) >> 9;
    float gamma = __uint_as_float(gamma_bits[g]);
    float scale = 128.0f / (gamma + EPS);
    const float lo = -128.0f + EPS, hi = 128.0f - EPS;
    float4 v = reinterpret_cast<const float4*>(x2)[idx];
    float4 o;
    o.x = fminf(hi, fmaxf(lo, v.x * scale));
    o.y = fminf(hi, fmaxf(lo, v.y * scale));
    o.z = fminf(hi, fmaxf(lo, v.z * scale));
    o.w = fminf(hi, fmaxf(lo, v.w * scale));
    reinterpret_cast<float4*>(qx)[idx] = o;
}

// ----------------------------- depthwise causal conv + SiLU -----------------
__global__ __launch_bounds__(256) void conv_silu_kernel(const float* __restrict__ xz,
                                                        const float* __restrict__ conv_w,
                                                        const float* __restrict__ conv_b,
                                                        float* __restrict__ xc) {
    int c = blockIdx.x * 256 + threadIdx.x;   // 0..2047
    int m = blockIdx.y;                        // token 0..4095
    int b = m >> 11, l = m & (SEQ - 1);
    float4 w4 = reinterpret_cast<const float4*>(conv_w)[c];
    float wv[4] = {w4.x, w4.y, w4.z, w4.w};
    float s = conv_b[c];
    const float* base = xz + ((size_t)b * SEQ) * 4096 + c;
    #pragma unroll
    for (int k = 0; k < 4; ++k) {
        int ll = l - 3 + k;
        if (ll >= 0) s += base[(size_t)ll * 4096] * wv[k];
    }
    float sig = 1.0f / (1.0f + __expf(-s));
    xc[(size_t)m * D_INNER + c] = s * sig;
}

// ----------------------------- selective scan (fused gate) ------------------
// one thread per (b, d); register double-buffered prefetch of next step
__global__ __launch_bounds__(64) void scan_kernel(const float* __restrict__ dt,
                                                  const float* __restrict__ xc,
                                                  const float* __restrict__ xdbl,
                                                  const float* __restrict__ xz,
                                                  const float* __restrict__ A_log,
                                                  const float* __restrict__ D_param,
                                                  float* __restrict__ y) {
    int ch = blockIdx.x * 64 + threadIdx.x;   // 0..4095
    int b = ch >> 11, d = ch & (D_INNER - 1);
    float a[D_STATE], h[D_STATE];
    #pragma unroll
    for (int s = 0; s < D_STATE; ++s) {
        a[s] = -__expf(A_log[(size_t)d * D_STATE + s]);
        h[s] = 0.0f;
    }
    float Dp = D_param[d];

    size_t m0 = (size_t)b * SEQ;
    // prefetch l = 0
    float dt_n = dt[m0 * D_INNER + d];
    float x_n  = xc[m0 * D_INNER + d];
    float z_n  = xz[m0 * 4096 + D_INNER + d];
    float4 B_n[4], C_n[4];
    {
        const float* xd = xdbl + m0 * 96;
        #pragma unroll
        for (int i = 0; i < 4; ++i) {
            B_n[i] = *reinterpret_cast<const float4*>(xd + DT_RANK + 4*i);
            C_n[i] = *reinterpret_cast<const float4*>(xd + DT_RANK + D_STATE + 4*i);
        }
    }

    for (int l = 0; l < SEQ; ++l) {
        float dtv = dt_n, xv = x_n, zv = z_n;
        float Bc[D_STATE], Cc[D_STATE];
        #pragma unroll
        for (int i = 0; i < 4; ++i) {
            Bc[4*i+0] = B_n[i].x; Bc[4*i+1] = B_n[i].y; Bc[4*i+2] = B_n[i].z; Bc[4*i+3] = B_n[i].w;
            Cc[4*i+0] = C_n[i].x; Cc[4*i+1] = C_n[i].y; Cc[4*i+2] = C_n[i].z; Cc[4*i+3] = C_n[i].w;
        }
        if (l + 1 < SEQ) {
            size_t m1 = m0 + l + 1;
            dt_n = dt[m1 * D_INNER + d];
            x_n  = xc[m1 * D_INNER + d];
            z_n  = xz[m1 * 4096 + D_INNER + d];
            const float* xd = xdbl + m1 * 96;
            #pragma unroll
            for (int i = 0; i < 4; ++i) {
                B_n[i] = *reinterpret_cast<const float4*>(xd + DT_RANK + 4*i);
                C_n[i] = *reinterpret_cast<const float4*>(xd + DT_RANK + D_STATE + 4*i);
            }
        }
        float dx = dtv * xv;
        float yv = 0.0f;
        #pragma unroll
        for (int s = 0; s < D_STATE; ++s) {
            float dA = __expf(dtv * a[s]);
            h[s] = h[s] * dA + dx * Bc[s];
            yv += h[s] * Cc[s];
        }
        yv += Dp * xv;
        float sig = 1.0f / (1.0f + __expf(-zv));
        size_t m = m0 + l;
        y[m * D_INNER + d] = yv * (zv * sig);
    }
}

// ----------------------------- launch ---------------------------------------
extern "C" void kernel_launch(void* const* d_in, const int* in_sizes, int n_in,
                              void* d_out, int out_size, void* d_ws, size_t ws_size,
                              hipStream_t stream) {
    const float* x         = (const float*)d_in[0];
    const float* ln1_g     = (const float*)d_in[1];
    const float* ln1_b     = (const float*)d_in[2];
    const float* ln2_g     = (const float*)d_in[3];
    const float* ln2_b     = (const float*)d_in[4];
    const float* W1        = (const float*)d_in[5];
    const float* b1        = (const float*)d_in[6];
    const float* W2        = (const float*)d_in[7];
    const float* b2        = (const float*)d_in[8];
    const float* in_proj   = (const float*)d_in[9];
    const float* conv_w    = (const float*)d_in[10];
    const float* conv_b    = (const float*)d_in[11];
    const float* x_proj    = (const float*)d_in[12];
    const float* dt_proj   = (const float*)d_in[13];
    const float* dt_proj_b = (const float*)d_in[14];
    const float* A_log     = (const float*)d_in[15];
    const float* D_param   = (const float*)d_in[16];
    const float* out_proj  = (const float*)d_in[17];
    float* out = (float*)d_out;

    // workspace layout (floats), buffers reused across phases:
    float* ws      = (float*)d_ws;
    float* f_ln    = ws;                        // 4,194,304  (ln1 -> u -> x_dbl)
    float* f_gated = f_ln    + 4194304;         // 8,388,608  (gated -> dt)
    float* f_x2    = f_gated + 8388608;         // 4,194,304  (x2 -> qx in-place)
    float* f_xz    = f_x2    + 4194304;         // 16,777,216 (xz: xs | z)
    float* f_xc    = f_xz    + 16777216;        // 8,388,608  (xs_conv -> y in-place)
    unsigned int* f_gamma = (unsigned int*)(f_xc + 8388608);  // 4

    dim3 b256(256);

    // 1. LN1
    ln_kernel<<<dim3(NTOK), b256, 0, stream>>>(x, ln1_g, ln1_b, f_ln);
    // 2. gated = clip(ln1 @ sign(W1)^T + b1)
    gemm_kernel<1, true><<<dim3(D_INNER/BNT, NTOK/BMT), b256, 0, stream>>>(
        f_ln, W1, f_gated, NTOK, D_INNER, D_MODEL, D_MODEL, D_INNER, b1, nullptr, 0);
    // 3. x2 = x + gated @ sign(W2)^T + b2
    gemm_kernel<2, true><<<dim3(D_MODEL/BNT, NTOK/BMT), b256, 0, stream>>>(
        f_gated, W2, f_x2, NTOK, D_MODEL, D_INNER, D_INNER, D_MODEL, b2, x, D_MODEL);
    // 4. groupwise quant (in-place)
    init_gamma_kernel<<<1, 64, 0, stream>>>(f_gamma);
    absmax_kernel<<<dim3(NTOK), b256, 0, stream>>>(f_x2, f_gamma);
    quant_kernel<<<dim3(NTOK*D_MODEL/4/256), b256, 0, stream>>>(f_x2, f_gamma, f_x2);
    // 5. LN2: u = LN(qx)
    ln_kernel<<<dim3(NTOK), b256, 0, stream>>>(f_x2, ln2_g, ln2_b, f_ln);
    // 6. xz = u @ in_proj^T
    gemm_kernel<0, false><<<dim3((2*D_INNER)/BNT, NTOK/BMT), b256, 0, stream>>>(
        f_ln, in_proj, f_xz, NTOK, 2*D_INNER, D_MODEL, D_MODEL, 2*D_INNER, nullptr, nullptr, 0);
    // 7. conv + silu
    conv_silu_kernel<<<dim3(D_INNER/256, NTOK), b256, 0, stream>>>(f_xz, conv_w, conv_b, f_xc);
    // 8. x_dbl = xs_conv @ x_proj^T   (N=96)
    gemm_kernel<0, false><<<dim3(1, NTOK/BMT), b256, 0, stream>>>(
        f_xc, x_proj, f_ln, NTOK, DT_RANK + 2*D_STATE, D_INNER, D_INNER, DT_RANK + 2*D_STATE,
        nullptr, nullptr, 0);
    // 9. dt = softplus(x_dbl[:, :64] @ dt_proj^T + dt_proj_b)
    gemm_kernel<3, false><<<dim3(D_INNER/BNT, NTOK/BMT), b256, 0, stream>>>(
        f_ln, dt_proj, f_gated, NTOK, D_INNER, DT_RANK, DT_RANK + 2*D_STATE, D_INNER,
        dt_proj_b, nullptr, 0);
    // 10. selective scan + D residual + silu(z) gate (y in-place over xs_conv)
    scan_kernel<<<dim3(64), dim3(64), 0, stream>>>(
        f_gated, f_xc, f_ln, f_xz, A_log, D_param, f_xc);
    // 11. out = qx + y @ out_proj^T
    gemm_kernel<4, false><<<dim3(D_MODEL/BNT, NTOK/BMT), b256, 0, stream>>>(
        f_xc, out_proj, out, NTOK, D_MODEL, D_INNER, D_INNER, D_MODEL, nullptr, f_x2, D_MODEL);
}

// Round 3
// 1974.797 us; speedup vs baseline: 1.5036x; 1.5036x over previous
//
#include <hip/hip_runtime.h>
#include <math.h>

#define D_MODEL 1024
#define D_INNER 2048
#define D_STATE 16
#define DT_RANK 64
#define D_CONV 4
#define BSZ 2
#define SEQ 2048
#define NTOK (BSZ*SEQ)   // 4096
#define NCH  (BSZ*D_INNER) // 4096 channels
#define NCHUNK 32
#define CLEN 64          // SEQ / NCHUNK
#define EPS 1e-5f

__device__ __forceinline__ float sgnf(float w) {
    return (w > 0.f) ? 1.f : ((w < 0.f) ? -1.f : 0.f);
}

// ----------------------------- LayerNorm ------------------------------------
__global__ __launch_bounds__(256) void ln_kernel(const float* __restrict__ x,
                                                 const float* __restrict__ g,
                                                 const float* __restrict__ b,
                                                 float* __restrict__ out) {
    int row = blockIdx.x, tid = threadIdx.x;
    float4 v = reinterpret_cast<const float4*>(x + (size_t)row * D_MODEL)[tid];
    float s = v.x + v.y + v.z + v.w;
    float q = v.x*v.x + v.y*v.y + v.z*v.z + v.w*v.w;
    #pragma unroll
    for (int off = 32; off > 0; off >>= 1) {
        s += __shfl_down(s, off);
        q += __shfl_down(q, off);
    }
    __shared__ float rs[4], rq[4], smean, srstd;
    if ((tid & 63) == 0) { rs[tid >> 6] = s; rq[tid >> 6] = q; }
    __syncthreads();
    if (tid == 0) {
        float ts = rs[0] + rs[1] + rs[2] + rs[3];
        float tq = rq[0] + rq[1] + rq[2] + rq[3];
        float mean = ts * (1.0f / D_MODEL);
        float var = tq * (1.0f / D_MODEL) - mean * mean;
        smean = mean;
        srstd = rsqrtf(var + EPS);
    }
    __syncthreads();
    float mean = smean, rstd = srstd;
    float4 gg = reinterpret_cast<const float4*>(g)[tid];
    float4 bb = reinterpret_cast<const float4*>(b)[tid];
    float4 o;
    o.x = (v.x - mean) * rstd * gg.x + bb.x;
    o.y = (v.y - mean) * rstd * gg.y + bb.y;
    o.z = (v.z - mean) * rstd * gg.z + bb.z;
    o.w = (v.w - mean) * rstd * gg.w + bb.w;
    reinterpret_cast<float4*>(out + (size_t)row * D_MODEL)[tid] = o;
}

// ----------------------------- GEMM -----------------------------------------
// C[M,N] = A[M,K] (row stride sA) @ W[N,K]^T  (+ epilogue)
// EP: 0 none | 1 +bias,clip[-1,1] | 2 +bias+addx | 3 softplus(acc+bias) | 4 +addx
#define BMT 128
#define BNT 128
#define BKT 16
#define LDT (BMT + 8)

template<int EP, bool SIGNW>
__global__ __launch_bounds__(256) void gemm_kernel(
    const float* __restrict__ A, const float* __restrict__ W, float* __restrict__ C,
    int M, int N, int K, int sA, int sC,
    const float* __restrict__ bias, const float* __restrict__ addx, int sAdd)
{
    __shared__ float As[BKT][LDT];
    __shared__ float Ws[BKT][LDT];
    int tid = threadIdx.x;
    int row0 = blockIdx.y * BMT, col0 = blockIdx.x * BNT;
    int tx = tid & 15, ty = tid >> 4;       // 16x16 thread grid, 8x8 each
    int lr = tid >> 1;                       // 0..127
    int lc = (tid & 1) * 8;                  // 0 or 8
    float acc[8][8] = {};

    for (int k0 = 0; k0 < K; k0 += BKT) {
        {
            int gr = row0 + lr;
            float4 v0 = {0,0,0,0}, v1 = {0,0,0,0};
            if (gr < M) {
                const float* p = A + (size_t)gr * sA + k0 + lc;
                v0 = *reinterpret_cast<const float4*>(p);
                v1 = *reinterpret_cast<const float4*>(p + 4);
            }
            As[lc+0][lr] = v0.x; As[lc+1][lr] = v0.y; As[lc+2][lr] = v0.z; As[lc+3][lr] = v0.w;
            As[lc+4][lr] = v1.x; As[lc+5][lr] = v1.y; As[lc+6][lr] = v1.z; As[lc+7][lr] = v1.w;
        }
        {
            int gn = col0 + lr;
            float4 v0 = {0,0,0,0}, v1 = {0,0,0,0};
            if (gn < N) {
                const float* p = W + (size_t)gn * K + k0 + lc;
                v0 = *reinterpret_cast<const float4*>(p);
                v1 = *reinterpret_cast<const float4*>(p + 4);
            }
            if (SIGNW) {
                v0.x = sgnf(v0.x); v0.y = sgnf(v0.y); v0.z = sgnf(v0.z); v0.w = sgnf(v0.w);
                v1.x = sgnf(v1.x); v1.y = sgnf(v1.y); v1.z = sgnf(v1.z); v1.w = sgnf(v1.w);
            }
            Ws[lc+0][lr] = v0.x; Ws[lc+1][lr] = v0.y; Ws[lc+2][lr] = v0.z; Ws[lc+3][lr] = v0.w;
            Ws[lc+4][lr] = v1.x; Ws[lc+5][lr] = v1.y; Ws[lc+6][lr] = v1.z; Ws[lc+7][lr] = v1.w;
        }
        __syncthreads();
        #pragma unroll
        for (int k = 0; k < BKT; ++k) {
            float4 a0 = *reinterpret_cast<const float4*>(&As[k][ty*8]);
            float4 a1 = *reinterpret_cast<const float4*>(&As[k][ty*8+4]);
            float4 w0 = *reinterpret_cast<const float4*>(&Ws[k][tx*8]);
            float4 w1 = *reinterpret_cast<const float4*>(&Ws[k][tx*8+4]);
            float av[8] = {a0.x,a0.y,a0.z,a0.w,a1.x,a1.y,a1.z,a1.w};
            float wv[8] = {w0.x,w0.y,w0.z,w0.w,w1.x,w1.y,w1.z,w1.w};
            #pragma unroll
            for (int i = 0; i < 8; ++i)
                #pragma unroll
                for (int j = 0; j < 8; ++j)
                    acc[i][j] += av[i] * wv[j];
        }
        __syncthreads();
    }

    #pragma unroll
    for (int i = 0; i < 8; ++i) {
        int gr = row0 + ty*8 + i;
        if (gr >= M) continue;
        #pragma unroll
        for (int j = 0; j < 8; ++j) {
            int gc = col0 + tx*8 + j;
            if (gc >= N) continue;
            float v = acc[i][j];
            if (EP == 1) { v += bias[gc]; v = fminf(1.0f, fmaxf(-1.0f, v)); }
            else if (EP == 2) { v += bias[gc] + addx[(size_t)gr*sAdd + gc]; }
            else if (EP == 3) { float t = v + bias[gc]; v = fmaxf(t, 0.0f) + log1pf(__expf(-fabsf(t))); }
            else if (EP == 4) { v += addx[(size_t)gr*sAdd + gc]; }
            C[(size_t)gr*sC + gc] = v;
        }
    }
}

// ----------------------------- groupwise abs-max + quant --------------------
__global__ __launch_bounds__(64) void init_gamma_kernel(unsigned int* g) {
    if (threadIdx.x < 4) g[threadIdx.x] = 0u;
}

__global__ __launch_bounds__(256) void absmax_kernel(const float* __restrict__ x2,
                                                     unsigned int* __restrict__ gamma_bits) {
    int m = blockIdx.x, tid = threadIdx.x;
    float4 v = reinterpret_cast<const float4*>(x2 + (size_t)m * D_MODEL)[tid];
    float mx = fmaxf(fmaxf(fabsf(v.x), fabsf(v.y)), fmaxf(fabsf(v.z), fabsf(v.w)));
    #pragma unroll
    for (int off = 32; off > 0; off >>= 1) mx = fmaxf(mx, __shfl_down(mx, off));
    __shared__ float red[4];
    if ((tid & 63) == 0) red[tid >> 6] = mx;
    __syncthreads();
    if (tid == 0) {
        float t = fmaxf(fmaxf(red[0], red[1]), fmaxf(red[2], red[3]));
        int g = (m & (SEQ - 1)) >> 9;   // group of 512 seq positions
        atomicMax(gamma_bits + g, __float_as_uint(t));
    }
}

__global__ __launch_bounds__(256) void quant_kernel(const float* __restrict__ x2,
                                                    const unsigned int* __restrict__ gamma_bits,
                                                    float* __restrict__ qx) {
    int idx = blockIdx.x * 256 + threadIdx.x;       // one float4 each
    int m = idx >> 8;                                // 256 float4 per row
    int g = (m & (SEQ - 1)) >> 9;
    float gamma = __uint_as_float(gamma_bits[g]);
    float scale = 128.0f / (gamma + EPS);
    const float lo = -128.0f + EPS, hi = 128.0f - EPS;
    float4 v = reinterpret_cast<const float4*>(x2)[idx];
    float4 o;
    o.x = fminf(hi, fmaxf(lo, v.x * scale));
    o.y = fminf(hi, fmaxf(lo, v.y * scale));
    o.z = fminf(hi, fmaxf(lo, v.z * scale));
    o.w = fminf(hi, fmaxf(lo, v.w * scale));
    reinterpret_cast<float4*>(qx)[idx] = o;
}

// ----------------------------- depthwise causal conv + SiLU -----------------
__global__ __launch_bounds__(256) void conv_silu_kernel(const float* __restrict__ xz,
                                                        const float* __restrict__ conv_w,
                                                        const float* __restrict__ conv_b,
                                                        float* __restrict__ xc) {
    int c = blockIdx.x * 256 + threadIdx.x;   // 0..2047
    int m = blockIdx.y;                        // token 0..4095
    int b = m >> 11, l = m & (SEQ - 1);
    float4 w4 = reinterpret_cast<const float4*>(conv_w)[c];
    float wv[4] = {w4.x, w4.y, w4.z, w4.w};
    float s = conv_b[c];
    const float* base = xz + ((size_t)b * SEQ) * 4096 + c;
    #pragma unroll
    for (int k = 0; k < 4; ++k) {
        int ll = l - 3 + k;
        if (ll >= 0) s += base[(size_t)ll * 4096] * wv[k];
    }
    float sig = 1.0f / (1.0f + __expf(-s));
    xc[(size_t)m * D_INNER + c] = s * sig;
}

// ----------------------------- chunked selective scan ------------------------
// Phase A: per (channel, chunk): local scan (h0=0) -> Lbuf[c][ch][16], Sbuf[c][ch]=sum(dt)
__global__ __launch_bounds__(256) void scan_partial_kernel(
    const float* __restrict__ dt, const float* __restrict__ xc,
    const float* __restrict__ xdbl, const float* __restrict__ A_log,
    float* __restrict__ Lbuf, float* __restrict__ Sbuf)
{
    int gtid = blockIdx.x * 256 + threadIdx.x;   // 0..131071
    int ch = gtid & (NCH - 1);
    int c  = gtid >> 12;                          // chunk index
    int b = ch >> 11, d = ch & (D_INNER - 1);
    float a[D_STATE], h[D_STATE];
    #pragma unroll
    for (int s = 0; s < D_STATE; ++s) {
        a[s] = -__expf(A_log[(size_t)d * D_STATE + s]);
        h[s] = 0.0f;
    }
    size_t m0 = (size_t)b * SEQ + (size_t)c * CLEN;
    float Ssum = 0.0f;

    float dt_n = dt[m0 * D_INNER + d];
    float x_n  = xc[m0 * D_INNER + d];
    float4 B_n[4];
    {
        const float* xd = xdbl + m0 * 96;
        #pragma unroll
        for (int i = 0; i < 4; ++i)
            B_n[i] = *reinterpret_cast<const float4*>(xd + DT_RANK + 4*i);
    }

    for (int l = 0; l < CLEN; ++l) {
        float dtv = dt_n, xv = x_n;
        float Bc[D_STATE];
        #pragma unroll
        for (int i = 0; i < 4; ++i) {
            Bc[4*i+0] = B_n[i].x; Bc[4*i+1] = B_n[i].y; Bc[4*i+2] = B_n[i].z; Bc[4*i+3] = B_n[i].w;
        }
        if (l + 1 < CLEN) {
            size_t m1 = m0 + l + 1;
            dt_n = dt[m1 * D_INNER + d];
            x_n  = xc[m1 * D_INNER + d];
            const float* xd = xdbl + m1 * 96;
            #pragma unroll
            for (int i = 0; i < 4; ++i)
                B_n[i] = *reinterpret_cast<const float4*>(xd + DT_RANK + 4*i);
        }
        Ssum += dtv;
        float dx = dtv * xv;
        #pragma unroll
        for (int s = 0; s < D_STATE; ++s) {
            float dA = __expf(dtv * a[s]);
            h[s] = h[s] * dA + dx * Bc[s];
        }
    }
    float4* Lp = reinterpret_cast<float4*>(Lbuf + (size_t)c * (NCH * D_STATE) + (size_t)ch * D_STATE);
    Lp[0] = make_float4(h[0], h[1], h[2], h[3]);
    Lp[1] = make_float4(h[4], h[5], h[6], h[7]);
    Lp[2] = make_float4(h[8], h[9], h[10], h[11]);
    Lp[3] = make_float4(h[12], h[13], h[14], h[15]);
    Sbuf[(size_t)c * NCH + ch] = Ssum;
}

// Phase B: sequential combine over chunks; rewrites Lbuf in place with chunk START states.
__global__ __launch_bounds__(256) void scan_combine_kernel(
    float* __restrict__ LH, const float* __restrict__ Sbuf,
    const float* __restrict__ A_log)
{
    int gtid = blockIdx.x * 256 + threadIdx.x;   // 0..65535
    int s = gtid & (D_STATE - 1);
    int ch = gtid >> 4;
    int d = ch & (D_INNER - 1);
    float a = -__expf(A_log[(size_t)d * D_STATE + s]);
    float h = 0.0f;
    #pragma unroll 4
    for (int c = 0; c < NCHUNK; ++c) {
        size_t idx = (size_t)c * (NCH * D_STATE) + (size_t)ch * D_STATE + s;
        float loc = LH[idx];
        LH[idx] = h;                              // start state for chunk c
        float P = __expf(a * Sbuf[(size_t)c * NCH + ch]);
        h = h * P + loc;
    }
}

// Phase C: re-run chunks from start states; emit y + D*x, gated by silu(z).
__global__ __launch_bounds__(256) void scan_final_kernel(
    const float* __restrict__ dt, const float* __restrict__ xc,
    const float* __restrict__ xdbl, const float* __restrict__ xz,
    const float* __restrict__ A_log, const float* __restrict__ D_param,
    const float* __restrict__ Hin, float* __restrict__ y)
{
    int gtid = blockIdx.x * 256 + threadIdx.x;   // 0..131071
    int ch = gtid & (NCH - 1);
    int c  = gtid >> 12;
    int b = ch >> 11, d = ch & (D_INNER - 1);
    float a[D_STATE], h[D_STATE];
    {
        const float4* Hp = reinterpret_cast<const float4*>(
            Hin + (size_t)c * (NCH * D_STATE) + (size_t)ch * D_STATE);
        float4 h0 = Hp[0], h1 = Hp[1], h2 = Hp[2], h3 = Hp[3];
        h[0]=h0.x; h[1]=h0.y; h[2]=h0.z; h[3]=h0.w;
        h[4]=h1.x; h[5]=h1.y; h[6]=h1.z; h[7]=h1.w;
        h[8]=h2.x; h[9]=h2.y; h[10]=h2.z; h[11]=h2.w;
        h[12]=h3.x; h[13]=h3.y; h[14]=h3.z; h[15]=h3.w;
    }
    #pragma unroll
    for (int s = 0; s < D_STATE; ++s)
        a[s] = -__expf(A_log[(size_t)d * D_STATE + s]);
    float Dp = D_param[d];

    size_t m0 = (size_t)b * SEQ + (size_t)c * CLEN;
    float dt_n = dt[m0 * D_INNER + d];
    float x_n  = xc[m0 * D_INNER + d];
    float z_n  = xz[m0 * 4096 + D_INNER + d];
    float4 B_n[4], C_n[4];
    {
        const float* xd = xdbl + m0 * 96;
        #pragma unroll
        for (int i = 0; i < 4; ++i) {
            B_n[i] = *reinterpret_cast<const float4*>(xd + DT_RANK + 4*i);
            C_n[i] = *reinterpret_cast<const float4*>(xd + DT_RANK + D_STATE + 4*i);
        }
    }

    for (int l = 0; l < CLEN; ++l) {
        float dtv = dt_n, xv = x_n, zv = z_n;
        float Bc[D_STATE], Cc[D_STATE];
        #pragma unroll
        for (int i = 0; i < 4; ++i) {
            Bc[4*i+0] = B_n[i].x; Bc[4*i+1] = B_n[i].y; Bc[4*i+2] = B_n[i].z; Bc[4*i+3] = B_n[i].w;
            Cc[4*i+0] = C_n[i].x; Cc[4*i+1] = C_n[i].y; Cc[4*i+2] = C_n[i].z; Cc[4*i+3] = C_n[i].w;
        }
        if (l + 1 < CLEN) {
            size_t m1 = m0 + l + 1;
            dt_n = dt[m1 * D_INNER + d];
            x_n  = xc[m1 * D_INNER + d];
            z_n  = xz[m1 * 4096 + D_INNER + d];
            const float* xd = xdbl + m1 * 96;
            #pragma unroll
            for (int i = 0; i < 4; ++i) {
                B_n[i] = *reinterpret_cast<const float4*>(xd + DT_RANK + 4*i);
                C_n[i] = *reinterpret_cast<const float4*>(xd + DT_RANK + D_STATE + 4*i);
            }
        }
        float dx = dtv * xv;
        float yv = 0.0f;
        #pragma unroll
        for (int s = 0; s < D_STATE; ++s) {
            float dA = __expf(dtv * a[s]);
            h[s] = h[s] * dA + dx * Bc[s];
            yv += h[s] * Cc[s];
        }
        yv += Dp * xv;
        float sig = 1.0f / (1.0f + __expf(-zv));
        size_t m = m0 + l;
        y[m * D_INNER + d] = yv * (zv * sig);
    }
}

// ----------------------------- launch ---------------------------------------
extern "C" void kernel_launch(void* const* d_in, const int* in_sizes, int n_in,
                              void* d_out, int out_size, void* d_ws, size_t ws_size,
                              hipStream_t stream) {
    const float* x         = (const float*)d_in[0];
    const float* ln1_g     = (const float*)d_in[1];
    const float* ln1_b     = (const float*)d_in[2];
    const float* ln2_g     = (const float*)d_in[3];
    const float* ln2_b     = (const float*)d_in[4];
    const float* W1        = (const float*)d_in[5];
    const float* b1        = (const float*)d_in[6];
    const float* W2        = (const float*)d_in[7];
    const float* b2        = (const float*)d_in[8];
    const float* in_proj   = (const float*)d_in[9];
    const float* conv_w    = (const float*)d_in[10];
    const float* conv_b    = (const float*)d_in[11];
    const float* x_proj    = (const float*)d_in[12];
    const float* dt_proj   = (const float*)d_in[13];
    const float* dt_proj_b = (const float*)d_in[14];
    const float* A_log     = (const float*)d_in[15];
    const float* D_param   = (const float*)d_in[16];
    const float* out_proj  = (const float*)d_in[17];
    float* out = (float*)d_out;

    // workspace layout (floats), buffers reused across phases:
    float* ws      = (float*)d_ws;
    float* f_ln    = ws;                        // 4,194,304  (ln1 -> u -> x_dbl + scan L/S slack)
    float* f_gated = f_ln    + 4194304;         // 8,388,608  (gated -> dt)
    float* f_x2    = f_gated + 8388608;         // 4,194,304  (x2 -> qx in-place)
    float* f_xz    = f_x2    + 4194304;         // 16,777,216 (xz: xs | z)
    float* f_xc    = f_xz    + 16777216;        // 8,388,608  (xs_conv -> y in-place)
    unsigned int* f_gamma = (unsigned int*)(f_xc + 8388608);  // 4
    // scan scratch inside f_ln slack (x_dbl uses only 4096*96 = 393,216 floats):
    float* f_L     = f_ln + 393216;             // 2,097,152 floats (L -> Hin in-place)
    float* f_S     = f_ln + 393216 + 2097152;   // 131,072 floats

    dim3 b256(256);

    // 1. LN1
    ln_kernel<<<dim3(NTOK), b256, 0, stream>>>(x, ln1_g, ln1_b, f_ln);
    // 2. gated = clip(ln1 @ sign(W1)^T + b1)
    gemm_kernel<1, true><<<dim3(D_INNER/BNT, NTOK/BMT), b256, 0, stream>>>(
        f_ln, W1, f_gated, NTOK, D_INNER, D_MODEL, D_MODEL, D_INNER, b1, nullptr, 0);
    // 3. x2 = x + gated @ sign(W2)^T + b2
    gemm_kernel<2, true><<<dim3(D_MODEL/BNT, NTOK/BMT), b256, 0, stream>>>(
        f_gated, W2, f_x2, NTOK, D_MODEL, D_INNER, D_INNER, D_MODEL, b2, x, D_MODEL);
    // 4. groupwise quant (in-place)
    init_gamma_kernel<<<1, 64, 0, stream>>>(f_gamma);
    absmax_kernel<<<dim3(NTOK), b256, 0, stream>>>(f_x2, f_gamma);
    quant_kernel<<<dim3(NTOK*D_MODEL/4/256), b256, 0, stream>>>(f_x2, f_gamma, f_x2);
    // 5. LN2: u = LN(qx)
    ln_kernel<<<dim3(NTOK), b256, 0, stream>>>(f_x2, ln2_g, ln2_b, f_ln);
    // 6. xz = u @ in_proj^T
    gemm_kernel<0, false><<<dim3((2*D_INNER)/BNT, NTOK/BMT), b256, 0, stream>>>(
        f_ln, in_proj, f_xz, NTOK, 2*D_INNER, D_MODEL, D_MODEL, 2*D_INNER, nullptr, nullptr, 0);
    // 7. conv + silu
    conv_silu_kernel<<<dim3(D_INNER/256, NTOK), b256, 0, stream>>>(f_xz, conv_w, conv_b, f_xc);
    // 8. x_dbl = xs_conv @ x_proj^T   (N=96)
    gemm_kernel<0, false><<<dim3(1, NTOK/BMT), b256, 0, stream>>>(
        f_xc, x_proj, f_ln, NTOK, DT_RANK + 2*D_STATE, D_INNER, D_INNER, DT_RANK + 2*D_STATE,
        nullptr, nullptr, 0);
    // 9. dt = softplus(x_dbl[:, :64] @ dt_proj^T + dt_proj_b)
    gemm_kernel<3, false><<<dim3(D_INNER/BNT, NTOK/BMT), b256, 0, stream>>>(
        f_ln, dt_proj, f_gated, NTOK, D_INNER, DT_RANK, DT_RANK + 2*D_STATE, D_INNER,
        dt_proj_b, nullptr, 0);
    // 10. chunked selective scan (A: partial, B: combine, C: final+gate)
    scan_partial_kernel<<<dim3(NCH*NCHUNK/256), b256, 0, stream>>>(
        f_gated, f_xc, f_ln, A_log, f_L, f_S);
    scan_combine_kernel<<<dim3(NCH*D_STATE/256), b256, 0, stream>>>(f_L, f_S, A_log);
    scan_final_kernel<<<dim3(NCH*NCHUNK/256), b256, 0, stream>>>(
        f_gated, f_xc, f_ln, f_xz, A_log, D_param, f_L, f_xc);
    // 11. out = qx + y @ out_proj^T
    gemm_kernel<4, false><<<dim3(D_MODEL/BNT, NTOK/BMT), b256, 0, stream>>>(
        f_xc, out_proj, out, NTOK, D_MODEL, D_INNER, D_INNER, D_MODEL, nullptr, f_x2, D_MODEL);
}

// Round 4
// 576.147 us; speedup vs baseline: 5.1539x; 3.4276x over previous
//
#include <hip/hip_runtime.h>
#include <math.h>

#define D_MODEL 1024
#define D_INNER 2048
#define D_STATE 16
#define DT_RANK 64
#define BSZ 2
#define SEQ 2048
#define NTOK (BSZ*SEQ)     // 4096
#define NCH  (BSZ*D_INNER) // 4096 channels
#define NCHUNK 32
#define CLEN 64            // SEQ / NCHUNK
#define EPS 1e-5f

typedef __attribute__((ext_vector_type(8))) short short8v;
typedef __attribute__((ext_vector_type(4))) float f32x4;

__device__ __forceinline__ float sgnf(float w) {
    return (w > 0.f) ? 1.f : ((w < 0.f) ? -1.f : 0.f);
}
__device__ __forceinline__ unsigned short f2bf(float f) {   // RNE fp32->bf16
    unsigned int x = __float_as_uint(f);
    x += 0x7fffu + ((x >> 16) & 1u);
    return (unsigned short)(x >> 16);
}
__device__ __forceinline__ float bf2f(unsigned short u) {
    return __uint_as_float(((unsigned int)u) << 16);
}
__device__ __forceinline__ void stage16(const unsigned short* g, unsigned short* l) {
    __builtin_amdgcn_global_load_lds(
        (const __attribute__((address_space(1))) unsigned int*)g,
        (__attribute__((address_space(3))) unsigned int*)l, 16, 0, 0);
}

// ----------------------------- weight converts ------------------------------
template<bool SIGN>
__global__ __launch_bounds__(256) void f2bf_kernel(const float* __restrict__ in,
                                                   unsigned short* __restrict__ outp, int n4) {
    int i = blockIdx.x * 256 + threadIdx.x;
    if (i >= n4) return;
    float4 v = reinterpret_cast<const float4*>(in)[i];
    if (SIGN) { v.x = sgnf(v.x); v.y = sgnf(v.y); v.z = sgnf(v.z); v.w = sgnf(v.w); }
    ushort4 o;
    o.x = f2bf(v.x); o.y = f2bf(v.y); o.z = f2bf(v.z); o.w = f2bf(v.w);
    reinterpret_cast<ushort4*>(outp)[i] = o;
}

// ----------------------------- LayerNorm variants ---------------------------
// LN producing hi/lo bf16 split (near-fp32 precision as hi+lo)
__global__ __launch_bounds__(256) void ln_hilo_kernel(const float* __restrict__ x,
                                                      const float* __restrict__ g,
                                                      const float* __restrict__ b,
                                                      unsigned short* __restrict__ hi,
                                                      unsigned short* __restrict__ lo) {
    int row = blockIdx.x, tid = threadIdx.x;
    float4 v = reinterpret_cast<const float4*>(x + (size_t)row * D_MODEL)[tid];
    float s = v.x + v.y + v.z + v.w;
    float q = v.x*v.x + v.y*v.y + v.z*v.z + v.w*v.w;
    #pragma unroll
    for (int off = 32; off > 0; off >>= 1) { s += __shfl_down(s, off); q += __shfl_down(q, off); }
    __shared__ float rs[4], rq[4], smean, srstd;
    if ((tid & 63) == 0) { rs[tid >> 6] = s; rq[tid >> 6] = q; }
    __syncthreads();
    if (tid == 0) {
        float ts = rs[0]+rs[1]+rs[2]+rs[3], tq = rq[0]+rq[1]+rq[2]+rq[3];
        float mean = ts * (1.0f / D_MODEL);
        smean = mean;
        srstd = rsqrtf(tq * (1.0f / D_MODEL) - mean*mean + EPS);
    }
    __syncthreads();
    float mean = smean, rstd = srstd;
    float4 gg = reinterpret_cast<const float4*>(g)[tid];
    float4 bb = reinterpret_cast<const float4*>(b)[tid];
    float o[4];
    o[0] = (v.x-mean)*rstd*gg.x + bb.x; o[1] = (v.y-mean)*rstd*gg.y + bb.y;
    o[2] = (v.z-mean)*rstd*gg.z + bb.z; o[3] = (v.w-mean)*rstd*gg.w + bb.w;
    ushort4 h4, l4;
    h4.x = f2bf(o[0]); l4.x = f2bf(o[0] - bf2f(h4.x));
    h4.y = f2bf(o[1]); l4.y = f2bf(o[1] - bf2f(h4.y));
    h4.z = f2bf(o[2]); l4.z = f2bf(o[2] - bf2f(h4.z));
    h4.w = f2bf(o[3]); l4.w = f2bf(o[3] - bf2f(h4.w));
    reinterpret_cast<ushort4*>(hi + (size_t)row * D_MODEL)[tid] = h4;
    reinterpret_cast<ushort4*>(lo + (size_t)row * D_MODEL)[tid] = l4;
}

// LN producing single bf16
__global__ __launch_bounds__(256) void ln_bf_kernel(const float* __restrict__ x,
                                                    const float* __restrict__ g,
                                                    const float* __restrict__ b,
                                                    unsigned short* __restrict__ outp) {
    int row = blockIdx.x, tid = threadIdx.x;
    float4 v = reinterpret_cast<const float4*>(x + (size_t)row * D_MODEL)[tid];
    float s = v.x + v.y + v.z + v.w;
    float q = v.x*v.x + v.y*v.y + v.z*v.z + v.w*v.w;
    #pragma unroll
    for (int off = 32; off > 0; off >>= 1) { s += __shfl_down(s, off); q += __shfl_down(q, off); }
    __shared__ float rs[4], rq[4], smean, srstd;
    if ((tid & 63) == 0) { rs[tid >> 6] = s; rq[tid >> 6] = q; }
    __syncthreads();
    if (tid == 0) {
        float ts = rs[0]+rs[1]+rs[2]+rs[3], tq = rq[0]+rq[1]+rq[2]+rq[3];
        float mean = ts * (1.0f / D_MODEL);
        smean = mean;
        srstd = rsqrtf(tq * (1.0f / D_MODEL) - mean*mean + EPS);
    }
    __syncthreads();
    float mean = smean, rstd = srstd;
    float4 gg = reinterpret_cast<const float4*>(g)[tid];
    float4 bb = reinterpret_cast<const float4*>(b)[tid];
    ushort4 o;
    o.x = f2bf((v.x-mean)*rstd*gg.x + bb.x);
    o.y = f2bf((v.y-mean)*rstd*gg.y + bb.y);
    o.z = f2bf((v.z-mean)*rstd*gg.z + bb.z);
    o.w = f2bf((v.w-mean)*rstd*gg.w + bb.w);
    reinterpret_cast<ushort4*>(outp + (size_t)row * D_MODEL)[tid] = o;
}

// ----------------------------- MFMA GEMM ------------------------------------
// C[M,N](+epilogue) = A[M,K]bf16 @ B[N,K]bf16^T   (m97 structure: 128x128 tile,
// BK=32, 4 waves 2x2, global_load_lds width16, ds_read_b128 frags)
// EP: 0 C=fp32 | 1 Cb=bf16 clip(v+bias) | 2 C=fp32 v+bias+addx | 3 C=fp32 softplus(v+bias)
//     4 C=fp32 v+addx | 5 C=fp32 v, and Cb[r*64+gc]=bf16(v) for gc<64
template<int EP, bool DUALA>
__global__ __launch_bounds__(256) void mfma_gemm(
    const unsigned short* __restrict__ A, const unsigned short* __restrict__ A2,
    const unsigned short* __restrict__ B, float* __restrict__ C,
    unsigned short* __restrict__ Cb,
    int M, int N, int K, int sA, int sC,
    const float* __restrict__ bias, const float* __restrict__ addx, int sAdd)
{
    __shared__ __align__(16) unsigned short As[128*32];
    __shared__ __align__(16) unsigned short As2[DUALA ? 128*32 : 8];
    __shared__ __align__(16) unsigned short Bs[128*32];
    const int tid = threadIdx.x;
    const int lane = tid & 63;
    const int w = tid >> 6;
    const int wm = w >> 1, wn = w & 1;
    const int row0 = blockIdx.y * 128, col0 = blockIdx.x * 128;
    const int srow = lane >> 2;            // 0..15
    const int scol = (lane & 3) * 8;       // 0,8,16,24

    f32x4 acc[4][4];
    #pragma unroll
    for (int m = 0; m < 4; ++m)
        #pragma unroll
        for (int n = 0; n < 4; ++n)
            acc[m][n] = (f32x4){0.f, 0.f, 0.f, 0.f};

    for (int k0 = 0; k0 < K; k0 += 32) {
        #pragma unroll
        for (int i = 0; i < 2; ++i) {
            const int rbase = w * 32 + i * 16;               // wave-uniform
            stage16(A + (size_t)(row0 + rbase + srow) * sA + k0 + scol, &As[rbase * 32]);
            if (DUALA)
                stage16(A2 + (size_t)(row0 + rbase + srow) * sA + k0 + scol, &As2[rbase * 32]);
            if (col0 + rbase < N)                            // N%16==0 in all uses
                stage16(B + (size_t)(col0 + rbase + srow) * K + k0 + scol, &Bs[rbase * 32]);
        }
        __syncthreads();                                     // drains vmcnt before LDS reads

        short8v af[4], bfr[4], af2[4];
        const int fr = lane & 15, kg = (lane >> 4) * 8;
        #pragma unroll
        for (int m = 0; m < 4; ++m)
            af[m] = *reinterpret_cast<const short8v*>(&As[(wm*64 + m*16 + fr) * 32 + kg]);
        if (DUALA) {
            #pragma unroll
            for (int m = 0; m < 4; ++m)
                af2[m] = *reinterpret_cast<const short8v*>(&As2[(wm*64 + m*16 + fr) * 32 + kg]);
        }
        #pragma unroll
        for (int n = 0; n < 4; ++n)
            bfr[n] = *reinterpret_cast<const short8v*>(&Bs[(wn*64 + n*16 + fr) * 32 + kg]);

        #pragma unroll
        for (int m = 0; m < 4; ++m)
            #pragma unroll
            for (int n = 0; n < 4; ++n) {
                acc[m][n] = __builtin_amdgcn_mfma_f32_16x16x32_bf16(af[m], bfr[n], acc[m][n], 0, 0, 0);
                if (DUALA)
                    acc[m][n] = __builtin_amdgcn_mfma_f32_16x16x32_bf16(af2[m], bfr[n], acc[m][n], 0, 0, 0);
            }
        __syncthreads();
    }

    // C/D layout (m89-verified): col = lane&15, row = (lane>>4)*4 + reg
    const int fc = lane & 15, r4 = (lane >> 4) * 4;
    #pragma unroll
    for (int m = 0; m < 4; ++m) {
        const int grb = row0 + wm*64 + m*16 + r4;
        #pragma unroll
        for (int n = 0; n < 4; ++n) {
            const int gc = col0 + wn*64 + n*16 + fc;
            if (gc >= N) continue;
            #pragma unroll
            for (int j = 0; j < 4; ++j) {
                const int r = grb + j;
                float v = acc[m][n][j];
                if (EP == 0) {
                    C[(size_t)r*sC + gc] = v;
                } else if (EP == 1) {
                    v += bias[gc];
                    v = fminf(1.0f, fmaxf(-1.0f, v));
                    Cb[(size_t)r*sC + gc] = f2bf(v);
                } else if (EP == 2) {
                    C[(size_t)r*sC + gc] = v + bias[gc] + addx[(size_t)r*sAdd + gc];
                } else if (EP == 3) {
                    float t = v + bias[gc];
                    C[(size_t)r*sC + gc] = fmaxf(t, 0.0f) + log1pf(__expf(-fabsf(t)));
                } else if (EP == 4) {
                    C[(size_t)r*sC + gc] = v + addx[(size_t)r*sAdd + gc];
                } else { // EP == 5
                    C[(size_t)r*sC + gc] = v;
                    if (gc < 64) Cb[(size_t)r*64 + gc] = f2bf(v);
                }
            }
        }
    }
}

// ----------------------------- groupwise abs-max + quant --------------------
__global__ __launch_bounds__(64) void init_gamma_kernel(unsigned int* g) {
    if (threadIdx.x < 4) g[threadIdx.x] = 0u;
}

__global__ __launch_bounds__(256) void absmax_kernel(const float* __restrict__ x2,
                                                     unsigned int* __restrict__ gamma_bits) {
    int m = blockIdx.x, tid = threadIdx.x;
    float4 v = reinterpret_cast<const float4*>(x2 + (size_t)m * D_MODEL)[tid];
    float mx = fmaxf(fmaxf(fabsf(v.x), fabsf(v.y)), fmaxf(fabsf(v.z), fabsf(v.w)));
    #pragma unroll
    for (int off = 32; off > 0; off >>= 1) mx = fmaxf(mx, __shfl_down(mx, off));
    __shared__ float red[4];
    if ((tid & 63) == 0) red[tid >> 6] = mx;
    __syncthreads();
    if (tid == 0) {
        float t = fmaxf(fmaxf(red[0], red[1]), fmaxf(red[2], red[3]));
        int g = (m & (SEQ - 1)) >> 9;
        atomicMax(gamma_bits + g, __float_as_uint(t));
    }
}

__global__ __launch_bounds__(256) void quant_kernel(const float* __restrict__ x2,
                                                    const unsigned int* __restrict__ gamma_bits,
                                                    float* __restrict__ qx) {
    int idx = blockIdx.x * 256 + threadIdx.x;
    int m = idx >> 8;
    int g = (m & (SEQ - 1)) >> 9;
    float gamma = __uint_as_float(gamma_bits[g]);
    float scale = 128.0f / (gamma + EPS);
    const float lo = -128.0f + EPS, hi = 128.0f - EPS;
    float4 v = reinterpret_cast<const float4*>(x2)[idx];
    float4 o;
    o.x = fminf(hi, fmaxf(lo, v.x * scale));
    o.y = fminf(hi, fmaxf(lo, v.y * scale));
    o.z = fminf(hi, fmaxf(lo, v.z * scale));
    o.w = fminf(hi, fmaxf(lo, v.w * scale));
    reinterpret_cast<float4*>(qx)[idx] = o;
}

// ----------------------------- depthwise causal conv + SiLU (bf16 out) ------
__global__ __launch_bounds__(256) void conv_silu_kernel(const float* __restrict__ xz,
                                                        const float* __restrict__ conv_w,
                                                        const float* __restrict__ conv_b,
                                                        unsigned short* __restrict__ xcb) {
    int c = blockIdx.x * 256 + threadIdx.x;   // 0..2047
    int m = blockIdx.y;                        // 0..4095
    int b = m >> 11, l = m & (SEQ - 1);
    float4 w4 = reinterpret_cast<const float4*>(conv_w)[c];
    float wv[4] = {w4.x, w4.y, w4.z, w4.w};
    float s = conv_b[c];
    const float* base = xz + ((size_t)b * SEQ) * 4096 + c;
    #pragma unroll
    for (int k = 0; k < 4; ++k) {
        int ll = l - 3 + k;
        if (ll >= 0) s += base[(size_t)ll * 4096] * wv[k];
    }
    float sig = 1.0f / (1.0f + __expf(-s));
    xcb[(size_t)m * D_INNER + c] = f2bf(s * sig);
}

// ----------------------------- chunked selective scan ------------------------
// dt lives in xz cols [0,2048); z in cols [2048,4096). x read from bf16 xcb.
__global__ __launch_bounds__(256) void scan_partial_kernel(
    const float* __restrict__ xz, const unsigned short* __restrict__ xcb,
    const float* __restrict__ xdbl, const float* __restrict__ A_log,
    float* __restrict__ Lbuf, float* __restrict__ Sbuf)
{
    int gtid = blockIdx.x * 256 + threadIdx.x;
    int ch = gtid & (NCH - 1);
    int c  = gtid >> 12;
    int b = ch >> 11, d = ch & (D_INNER - 1);
    float a[D_STATE], h[D_STATE];
    #pragma unroll
    for (int s = 0; s < D_STATE; ++s) {
        a[s] = -__expf(A_log[(size_t)d * D_STATE + s]);
        h[s] = 0.0f;
    }
    size_t m0 = (size_t)b * SEQ + (size_t)c * CLEN;
    float Ssum = 0.0f;

    float dt_n = xz[m0 * 4096 + d];
    float x_n  = bf2f(xcb[m0 * D_INNER + d]);
    float4 B_n[4];
    {
        const float* xd = xdbl + m0 * 96;
        #pragma unroll
        for (int i = 0; i < 4; ++i)
            B_n[i] = *reinterpret_cast<const float4*>(xd + DT_RANK + 4*i);
    }

    for (int l = 0; l < CLEN; ++l) {
        float dtv = dt_n, xv = x_n;
        float Bc[D_STATE];
        #pragma unroll
        for (int i = 0; i < 4; ++i) {
            Bc[4*i+0] = B_n[i].x; Bc[4*i+1] = B_n[i].y; Bc[4*i+2] = B_n[i].z; Bc[4*i+3] = B_n[i].w;
        }
        if (l + 1 < CLEN) {
            size_t m1 = m0 + l + 1;
            dt_n = xz[m1 * 4096 + d];
            x_n  = bf2f(xcb[m1 * D_INNER + d]);
            const float* xd = xdbl + m1 * 96;
            #pragma unroll
            for (int i = 0; i < 4; ++i)
                B_n[i] = *reinterpret_cast<const float4*>(xd + DT_RANK + 4*i);
        }
        Ssum += dtv;
        float dx = dtv * xv;
        #pragma unroll
        for (int s = 0; s < D_STATE; ++s) {
            float dA = __expf(dtv * a[s]);
            h[s] = h[s] * dA + dx * Bc[s];
        }
    }
    float4* Lp = reinterpret_cast<float4*>(Lbuf + (size_t)c * (NCH * D_STATE) + (size_t)ch * D_STATE);
    Lp[0] = make_float4(h[0], h[1], h[2], h[3]);
    Lp[1] = make_float4(h[4], h[5], h[6], h[7]);
    Lp[2] = make_float4(h[8], h[9], h[10], h[11]);
    Lp[3] = make_float4(h[12], h[13], h[14], h[15]);
    Sbuf[(size_t)c * NCH + ch] = Ssum;
}

__global__ __launch_bounds__(256) void scan_combine_kernel(
    float* __restrict__ LH, const float* __restrict__ Sbuf,
    const float* __restrict__ A_log)
{
    int gtid = blockIdx.x * 256 + threadIdx.x;
    int s = gtid & (D_STATE - 1);
    int ch = gtid >> 4;
    int d = ch & (D_INNER - 1);
    float a = -__expf(A_log[(size_t)d * D_STATE + s]);
    float h = 0.0f;
    #pragma unroll 4
    for (int c = 0; c < NCHUNK; ++c) {
        size_t idx = (size_t)c * (NCH * D_STATE) + (size_t)ch * D_STATE + s;
        float loc = LH[idx];
        LH[idx] = h;
        float P = __expf(a * Sbuf[(size_t)c * NCH + ch]);
        h = h * P + loc;
    }
}

__global__ __launch_bounds__(256) void scan_final_kernel(
    const float* __restrict__ xz, const unsigned short* __restrict__ xcb,
    const float* __restrict__ xdbl, const float* __restrict__ A_log,
    const float* __restrict__ D_param, const float* __restrict__ Hin,
    unsigned short* __restrict__ yb)
{
    int gtid = blockIdx.x * 256 + threadIdx.x;
    int ch = gtid & (NCH - 1);
    int c  = gtid >> 12;
    int b = ch >> 11, d = ch & (D_INNER - 1);
    float a[D_STATE], h[D_STATE];
    {
        const float4* Hp = reinterpret_cast<const float4*>(
            Hin + (size_t)c * (NCH * D_STATE) + (size_t)ch * D_STATE);
        float4 h0 = Hp[0], h1 = Hp[1], h2 = Hp[2], h3 = Hp[3];
        h[0]=h0.x; h[1]=h0.y; h[2]=h0.z; h[3]=h0.w;
        h[4]=h1.x; h[5]=h1.y; h[6]=h1.z; h[7]=h1.w;
        h[8]=h2.x; h[9]=h2.y; h[10]=h2.z; h[11]=h2.w;
        h[12]=h3.x; h[13]=h3.y; h[14]=h3.z; h[15]=h3.w;
    }
    #pragma unroll
    for (int s = 0; s < D_STATE; ++s)
        a[s] = -__expf(A_log[(size_t)d * D_STATE + s]);
    float Dp = D_param[d];

    size_t m0 = (size_t)b * SEQ + (size_t)c * CLEN;
    float dt_n = xz[m0 * 4096 + d];
    float x_n  = bf2f(xcb[m0 * D_INNER + d]);
    float z_n  = xz[m0 * 4096 + D_INNER + d];
    float4 B_n[4], C_n[4];
    {
        const float* xd = xdbl + m0 * 96;
        #pragma unroll
        for (int i = 0; i < 4; ++i) {
            B_n[i] = *reinterpret_cast<const float4*>(xd + DT_RANK + 4*i);
            C_n[i] = *reinterpret_cast<const float4*>(xd + DT_RANK + D_STATE + 4*i);
        }
    }

    for (int l = 0; l < CLEN; ++l) {
        float dtv = dt_n, xv = x_n, zv = z_n;
        float Bc[D_STATE], Cc[D_STATE];
        #pragma unroll
        for (int i = 0; i < 4; ++i) {
            Bc[4*i+0] = B_n[i].x; Bc[4*i+1] = B_n[i].y; Bc[4*i+2] = B_n[i].z; Bc[4*i+3] = B_n[i].w;
            Cc[4*i+0] = C_n[i].x; Cc[4*i+1] = C_n[i].y; Cc[4*i+2] = C_n[i].z; Cc[4*i+3] = C_n[i].w;
        }
        if (l + 1 < CLEN) {
            size_t m1 = m0 + l + 1;
            dt_n = xz[m1 * 4096 + d];
            x_n  = bf2f(xcb[m1 * D_INNER + d]);
            z_n  = xz[m1 * 4096 + D_INNER + d];
            const float* xd = xdbl + m1 * 96;
            #pragma unroll
            for (int i = 0; i < 4; ++i) {
                B_n[i] = *reinterpret_cast<const float4*>(xd + DT_RANK + 4*i);
                C_n[i] = *reinterpret_cast<const float4*>(xd + DT_RANK + D_STATE + 4*i);
            }
        }
        float dx = dtv * xv;
        float yv = 0.0f;
        #pragma unroll
        for (int s = 0; s < D_STATE; ++s) {
            float dA = __expf(dtv * a[s]);
            h[s] = h[s] * dA + dx * Bc[s];
            yv += h[s] * Cc[s];
        }
        yv += Dp * xv;
        float sig = 1.0f / (1.0f + __expf(-zv));
        yb[(m0 + l) * D_INNER + d] = f2bf(yv * (zv * sig));
    }
}

// ----------------------------- launch ---------------------------------------
extern "C" void kernel_launch(void* const* d_in, const int* in_sizes, int n_in,
                              void* d_out, int out_size, void* d_ws, size_t ws_size,
                              hipStream_t stream) {
    const float* x         = (const float*)d_in[0];
    const float* ln1_g     = (const float*)d_in[1];
    const float* ln1_b     = (const float*)d_in[2];
    const float* ln2_g     = (const float*)d_in[3];
    const float* ln2_b     = (const float*)d_in[4];
    const float* W1        = (const float*)d_in[5];
    const float* b1        = (const float*)d_in[6];
    const float* W2        = (const float*)d_in[7];
    const float* b2        = (const float*)d_in[8];
    const float* in_proj   = (const float*)d_in[9];
    const float* conv_w    = (const float*)d_in[10];
    const float* conv_b    = (const float*)d_in[11];
    const float* x_proj    = (const float*)d_in[12];
    const float* dt_proj   = (const float*)d_in[13];
    const float* dt_proj_b = (const float*)d_in[14];
    const float* A_log     = (const float*)d_in[15];
    const float* D_param   = (const float*)d_in[16];
    const float* out_proj  = (const float*)d_in[17];
    float* out = (float*)d_out;

    // ---- workspace layout (bytes) — 151 MiB total, < 168 MiB known-good ----
    char* ws = (char*)d_ws;
    float* f_x2   = (float*)(ws + 0);                 // 16,777,216  x2 -> qx in-place
    float* f_xz   = (float*)(ws + 16777216);          // 67,108,864  [xs|z]; xs cols become dt
    float* f_xdbl = (float*)(ws + 83886080);          //  1,572,864  x_dbl fp32
    float* f_L    = (float*)(ws + 85458944);          //  8,388,608
    float* f_S    = (float*)(ws + 93847552);          //    524,288
    unsigned int* f_gamma = (unsigned int*)(ws + 94371840);  // 64
    unsigned short* b_a1hi = (unsigned short*)(ws + 94371904);   // 8,388,608
    unsigned short* b_a1lo = b_a1hi + 4194304;                    // 8,388,608
    unsigned short* b_y    = b_a1hi;                              // reuse (16 MB)
    unsigned short* b_gated= b_a1lo + 4194304;                    // 16,777,216
    unsigned short* b_xc   = b_gated;                             // reuse
    unsigned short* b_u    = b_gated + 8388608;                   // 8,388,608
    unsigned short* b_xdt  = b_u;                                 // reuse (512 KB)
    unsigned short* b_w1s  = b_u    + 4194304;                    // 4,194,304
    unsigned short* b_w2s  = b_w1s  + 2097152;                    // 4,194,304
    unsigned short* b_inpj = b_w2s  + 2097152;                    // 8,388,608
    unsigned short* b_xpj  = b_inpj + 4194304;                    //   393,216
    unsigned short* b_dtpj = b_xpj  + 196608;                     //   262,144
    unsigned short* b_outpj= b_dtpj + 131072;                     // 4,194,304

    dim3 b256(256);

    // 0. weight conversions (every call; no static state)
    f2bf_kernel<true ><<<dim3(2048), b256, 0, stream>>>(W1, b_w1s, 524288);
    f2bf_kernel<true ><<<dim3(2048), b256, 0, stream>>>(W2, b_w2s, 524288);
    f2bf_kernel<false><<<dim3(4096), b256, 0, stream>>>(in_proj, b_inpj, 1048576);
    f2bf_kernel<false><<<dim3(192),  b256, 0, stream>>>(x_proj, b_xpj, 49152);
    f2bf_kernel<false><<<dim3(128),  b256, 0, stream>>>(dt_proj, b_dtpj, 32768);
    f2bf_kernel<false><<<dim3(2048), b256, 0, stream>>>(out_proj, b_outpj, 524288);

    // 1. LN1 -> hi/lo bf16
    ln_hilo_kernel<<<dim3(NTOK), b256, 0, stream>>>(x, ln1_g, ln1_b, b_a1hi, b_a1lo);
    // 2. gated = clip((hi+lo) @ sign(W1)^T + b1) -> bf16
    mfma_gemm<1, true><<<dim3(16, 32), b256, 0, stream>>>(
        b_a1hi, b_a1lo, b_w1s, nullptr, b_gated, NTOK, D_INNER, D_MODEL, D_MODEL, D_INNER,
        b1, nullptr, 0);
    // 3. x2 = gated @ sign(W2)^T + b2 + x -> fp32
    mfma_gemm<2, false><<<dim3(8, 32), b256, 0, stream>>>(
        b_gated, nullptr, b_w2s, f_x2, nullptr, NTOK, D_MODEL, D_INNER, D_INNER, D_MODEL,
        b2, x, D_MODEL);
    // 4. groupwise quant (in-place)
    init_gamma_kernel<<<1, 64, 0, stream>>>(f_gamma);
    absmax_kernel<<<dim3(NTOK), b256, 0, stream>>>(f_x2, f_gamma);
    quant_kernel<<<dim3(NTOK*D_MODEL/4/256), b256, 0, stream>>>(f_x2, f_gamma, f_x2);
    // 5. LN2 -> bf16
    ln_bf_kernel<<<dim3(NTOK), b256, 0, stream>>>(f_x2, ln2_g, ln2_b, b_u);
    // 6. xz = u @ in_proj^T -> fp32
    mfma_gemm<0, false><<<dim3(32, 32), b256, 0, stream>>>(
        b_u, nullptr, b_inpj, f_xz, nullptr, NTOK, 2*D_INNER, D_MODEL, D_MODEL, 2*D_INNER,
        nullptr, nullptr, 0);
    // 7. conv + silu -> bf16 xc
    conv_silu_kernel<<<dim3(D_INNER/256, NTOK), b256, 0, stream>>>(f_xz, conv_w, conv_b, b_xc);
    // 8. x_dbl = xc @ x_proj^T -> fp32 (+ bf16 dt-cols)
    mfma_gemm<5, false><<<dim3(1, 32), b256, 0, stream>>>(
        b_xc, nullptr, b_xpj, f_xdbl, b_xdt, NTOK, DT_RANK + 2*D_STATE, D_INNER, D_INNER,
        DT_RANK + 2*D_STATE, nullptr, nullptr, 0);
    // 9. dt = softplus(xdt @ dt_proj^T + b) -> fp32, aliased into xz cols [0,2048)
    mfma_gemm<3, false><<<dim3(16, 32), b256, 0, stream>>>(
        b_xdt, nullptr, b_dtpj, f_xz, nullptr, NTOK, D_INNER, DT_RANK, DT_RANK, 4096,
        dt_proj_b, nullptr, 0);
    // 10. chunked scan (dt & z both read from f_xz)
    scan_partial_kernel<<<dim3(NCH*NCHUNK/256), b256, 0, stream>>>(
        f_xz, b_xc, f_xdbl, A_log, f_L, f_S);
    scan_combine_kernel<<<dim3(NCH*D_STATE/256), b256, 0, stream>>>(f_L, f_S, A_log);
    scan_final_kernel<<<dim3(NCH*NCHUNK/256), b256, 0, stream>>>(
        f_xz, b_xc, f_xdbl, A_log, D_param, f_L, b_y);
    // 11. out = y @ out_proj^T + qx -> fp32
    mfma_gemm<4, false><<<dim3(8, 32), b256, 0, stream>>>(
        b_y, nullptr, b_outpj, out, nullptr, NTOK, D_MODEL, D_INNER, D_INNER, D_MODEL,
        nullptr, f_x2, D_MODEL);
}

// Round 5
// 501.961 us; speedup vs baseline: 5.9156x; 1.1478x over previous
//
#include <hip/hip_runtime.h>
#include <math.h>

#define D_MODEL 1024
#define D_INNER 2048
#define D_STATE 16
#define DT_RANK 64
#define BSZ 2
#define SEQ 2048
#define NTOK (BSZ*SEQ)     // 4096
#define NCH  (BSZ*D_INNER) // 4096 channels
#define NCHUNK 64
#define CLEN 32            // SEQ / NCHUNK
#define EPS 1e-5f

typedef __attribute__((ext_vector_type(8))) short short8v;
typedef __attribute__((ext_vector_type(4))) float f32x4;

__device__ __forceinline__ float sgnf(float w) {
    return (w > 0.f) ? 1.f : ((w < 0.f) ? -1.f : 0.f);
}
__device__ __forceinline__ unsigned short f2bf(float f) {   // RNE fp32->bf16
    unsigned int x = __float_as_uint(f);
    x += 0x7fffu + ((x >> 16) & 1u);
    return (unsigned short)(x >> 16);
}
__device__ __forceinline__ float bf2f(unsigned short u) {
    return __uint_as_float(((unsigned int)u) << 16);
}
__device__ __forceinline__ void stage16(const unsigned short* g, unsigned short* l) {
    __builtin_amdgcn_global_load_lds(
        (const __attribute__((address_space(1))) unsigned int*)g,
        (__attribute__((address_space(3))) unsigned int*)l, 16, 0, 0);
}

// ------------------- merged weight conversion (6 tensors, 1 launch) ---------
// float4 counts: W1 524288 | W2 524288 | inpj 1048576 | xpj 49152 | dtpj 32768 | outpj 524288
#define F4_W1   524288
#define F4_C1   524288
#define F4_C2   1048576
#define F4_C3   2097152
#define F4_C4   2146304
#define F4_C5   2179072
#define F4_C6   2703360
__global__ __launch_bounds__(256) void f2bf_all_kernel(
    const float* __restrict__ W1, const float* __restrict__ W2,
    const float* __restrict__ inpj, const float* __restrict__ xpj,
    const float* __restrict__ dtpj, const float* __restrict__ outpj,
    unsigned short* __restrict__ o_w1, unsigned short* __restrict__ o_w2,
    unsigned short* __restrict__ o_in, unsigned short* __restrict__ o_xp,
    unsigned short* __restrict__ o_dt, unsigned short* __restrict__ o_out)
{
    int i = blockIdx.x * 256 + threadIdx.x;
    if (i >= F4_C6) return;
    const float* src; unsigned short* dst; int off; bool sign = false;
    if (i < F4_C1)      { src = W1;   dst = o_w1;  off = i;          sign = true; }
    else if (i < F4_C2) { src = W2;   dst = o_w2;  off = i - F4_C1;  sign = true; }
    else if (i < F4_C3) { src = inpj; dst = o_in;  off = i - F4_C2; }
    else if (i < F4_C4) { src = xpj;  dst = o_xp;  off = i - F4_C3; }
    else if (i < F4_C5) { src = dtpj; dst = o_dt;  off = i - F4_C4; }
    else                { src = outpj;dst = o_out; off = i - F4_C5; }
    float4 v = reinterpret_cast<const float4*>(src)[off];
    if (sign) { v.x = sgnf(v.x); v.y = sgnf(v.y); v.z = sgnf(v.z); v.w = sgnf(v.w); }
    ushort4 o;
    o.x = f2bf(v.x); o.y = f2bf(v.y); o.z = f2bf(v.z); o.w = f2bf(v.w);
    reinterpret_cast<ushort4*>(dst)[off] = o;
}

// ----------------------------- LN1 -> hi/lo bf16 ----------------------------
__global__ __launch_bounds__(256) void ln_hilo_kernel(const float* __restrict__ x,
                                                      const float* __restrict__ g,
                                                      const float* __restrict__ b,
                                                      unsigned short* __restrict__ hi,
                                                      unsigned short* __restrict__ lo) {
    int row = blockIdx.x, tid = threadIdx.x;
    float4 v = reinterpret_cast<const float4*>(x + (size_t)row * D_MODEL)[tid];
    float s = v.x + v.y + v.z + v.w;
    float q = v.x*v.x + v.y*v.y + v.z*v.z + v.w*v.w;
    #pragma unroll
    for (int off = 32; off > 0; off >>= 1) { s += __shfl_down(s, off); q += __shfl_down(q, off); }
    __shared__ float rs[4], rq[4], smean, srstd;
    if ((tid & 63) == 0) { rs[tid >> 6] = s; rq[tid >> 6] = q; }
    __syncthreads();
    if (tid == 0) {
        float ts = rs[0]+rs[1]+rs[2]+rs[3], tq = rq[0]+rq[1]+rq[2]+rq[3];
        float mean = ts * (1.0f / D_MODEL);
        smean = mean;
        srstd = rsqrtf(tq * (1.0f / D_MODEL) - mean*mean + EPS);
    }
    __syncthreads();
    float mean = smean, rstd = srstd;
    float4 gg = reinterpret_cast<const float4*>(g)[tid];
    float4 bb = reinterpret_cast<const float4*>(b)[tid];
    float o[4];
    o[0] = (v.x-mean)*rstd*gg.x + bb.x; o[1] = (v.y-mean)*rstd*gg.y + bb.y;
    o[2] = (v.z-mean)*rstd*gg.z + bb.z; o[3] = (v.w-mean)*rstd*gg.w + bb.w;
    ushort4 h4, l4;
    h4.x = f2bf(o[0]); l4.x = f2bf(o[0] - bf2f(h4.x));
    h4.y = f2bf(o[1]); l4.y = f2bf(o[1] - bf2f(h4.y));
    h4.z = f2bf(o[2]); l4.z = f2bf(o[2] - bf2f(h4.z));
    h4.w = f2bf(o[3]); l4.w = f2bf(o[3] - bf2f(h4.w));
    reinterpret_cast<ushort4*>(hi + (size_t)row * D_MODEL)[tid] = h4;
    reinterpret_cast<ushort4*>(lo + (size_t)row * D_MODEL)[tid] = l4;
}

// ----------------------------- MFMA GEMM ------------------------------------
// C[M,N](+epilogue) = A[M,K]bf16 @ B[N,K]bf16^T   (m97 structure)
// EP: 0 C=fp32 | 1 Cb=bf16 clip(v+bias) | 3 C=fp32 softplus(v+bias) | 4 C=fp32 v+addx
//     5 C=fp32 v + Cb[r*64+gc] bf16 for gc<64 | 6 Cb=bf16 v | 7 C=fp32 v+bias+addx, absmax->gma
template<int EP, bool DUALA>
__global__ __launch_bounds__(256) void mfma_gemm(
    const unsigned short* __restrict__ A, const unsigned short* __restrict__ A2,
    const unsigned short* __restrict__ B, float* __restrict__ C,
    unsigned short* __restrict__ Cb,
    int M, int N, int K, int sA, int sC,
    const float* __restrict__ bias, const float* __restrict__ addx, int sAdd,
    unsigned int* __restrict__ gma)
{
    __shared__ __align__(16) unsigned short As[128*32];
    __shared__ __align__(16) unsigned short As2[DUALA ? 128*32 : 8];
    __shared__ __align__(16) unsigned short Bs[128*32];
    __shared__ float redmax[4];
    const int tid = threadIdx.x;
    const int lane = tid & 63;
    const int w = tid >> 6;
    const int wm = w >> 1, wn = w & 1;
    const int row0 = blockIdx.y * 128, col0 = blockIdx.x * 128;
    const int srow = lane >> 2;            // 0..15
    const int scol = (lane & 3) * 8;       // 0,8,16,24

    f32x4 acc[4][4];
    #pragma unroll
    for (int m = 0; m < 4; ++m)
        #pragma unroll
        for (int n = 0; n < 4; ++n)
            acc[m][n] = (f32x4){0.f, 0.f, 0.f, 0.f};

    for (int k0 = 0; k0 < K; k0 += 32) {
        #pragma unroll
        for (int i = 0; i < 2; ++i) {
            const int rbase = w * 32 + i * 16;               // wave-uniform
            stage16(A + (size_t)(row0 + rbase + srow) * sA + k0 + scol, &As[rbase * 32]);
            if (DUALA)
                stage16(A2 + (size_t)(row0 + rbase + srow) * sA + k0 + scol, &As2[rbase * 32]);
            if (col0 + rbase < N)                            // N%16==0 in all uses
                stage16(B + (size_t)(col0 + rbase + srow) * K + k0 + scol, &Bs[rbase * 32]);
        }
        __syncthreads();                                     // drains vmcnt before LDS reads

        short8v af[4], bfr[4], af2[4];
        const int fr = lane & 15, kg = (lane >> 4) * 8;
        #pragma unroll
        for (int m = 0; m < 4; ++m)
            af[m] = *reinterpret_cast<const short8v*>(&As[(wm*64 + m*16 + fr) * 32 + kg]);
        if (DUALA) {
            #pragma unroll
            for (int m = 0; m < 4; ++m)
                af2[m] = *reinterpret_cast<const short8v*>(&As2[(wm*64 + m*16 + fr) * 32 + kg]);
        }
        #pragma unroll
        for (int n = 0; n < 4; ++n)
            bfr[n] = *reinterpret_cast<const short8v*>(&Bs[(wn*64 + n*16 + fr) * 32 + kg]);

        #pragma unroll
        for (int m = 0; m < 4; ++m)
            #pragma unroll
            for (int n = 0; n < 4; ++n) {
                acc[m][n] = __builtin_amdgcn_mfma_f32_16x16x32_bf16(af[m], bfr[n], acc[m][n], 0, 0, 0);
                if (DUALA)
                    acc[m][n] = __builtin_amdgcn_mfma_f32_16x16x32_bf16(af2[m], bfr[n], acc[m][n], 0, 0, 0);
            }
        __syncthreads();
    }

    // C/D layout (m89-verified): col = lane&15, row = (lane>>4)*4 + reg
    const int fc = lane & 15, r4 = (lane >> 4) * 4;
    float lmax = 0.0f;
    #pragma unroll
    for (int m = 0; m < 4; ++m) {
        const int grb = row0 + wm*64 + m*16 + r4;
        #pragma unroll
        for (int n = 0; n < 4; ++n) {
            const int gc = col0 + wn*64 + n*16 + fc;
            if (gc >= N) continue;
            #pragma unroll
            for (int j = 0; j < 4; ++j) {
                const int r = grb + j;
                float v = acc[m][n][j];
                if (EP == 0) {
                    C[(size_t)r*sC + gc] = v;
                } else if (EP == 1) {
                    v += bias[gc];
                    v = fminf(1.0f, fmaxf(-1.0f, v));
                    Cb[(size_t)r*sC + gc] = f2bf(v);
                } else if (EP == 3) {
                    float t = v + bias[gc];
                    C[(size_t)r*sC + gc] = fmaxf(t, 0.0f) + log1pf(__expf(-fabsf(t)));
                } else if (EP == 4) {
                    C[(size_t)r*sC + gc] = v + addx[(size_t)r*sAdd + gc];
                } else if (EP == 5) {
                    C[(size_t)r*sC + gc] = v;
                    if (gc < 64) Cb[(size_t)r*64 + gc] = f2bf(v);
                } else if (EP == 6) {
                    Cb[(size_t)r*sC + gc] = f2bf(v);
                } else { // EP == 7
                    v += bias[gc] + addx[(size_t)r*sAdd + gc];
                    C[(size_t)r*sC + gc] = v;
                    lmax = fmaxf(lmax, fabsf(v));
                }
            }
        }
    }
    if (EP == 7) {
        #pragma unroll
        for (int off = 32; off > 0; off >>= 1) lmax = fmaxf(lmax, __shfl_down(lmax, off));
        if (lane == 0) redmax[w] = lmax;
        __syncthreads();
        if (tid == 0) {
            float t = fmaxf(fmaxf(redmax[0], redmax[1]), fmaxf(redmax[2], redmax[3]));
            int g = (row0 & (SEQ - 1)) >> 9;   // 128-row tile lies in one 512-group
            atomicMax(gma + g, __float_as_uint(t));
        }
    }
}

// ----------------------------- gamma init -----------------------------------
__global__ __launch_bounds__(64) void init_gamma_kernel(unsigned int* g) {
    if (threadIdx.x < 4) g[threadIdx.x] = 0u;
}

// ------------------- fused quant + LN2 (qx fp32 + u bf16) -------------------
__global__ __launch_bounds__(256) void quant_ln_kernel(
    const float* __restrict__ x2, const unsigned int* __restrict__ gamma_bits,
    const float* __restrict__ g, const float* __restrict__ b,
    float* __restrict__ qx, unsigned short* __restrict__ u)
{
    int row = blockIdx.x, tid = threadIdx.x;
    int grp = (row & (SEQ - 1)) >> 9;
    float gamma = __uint_as_float(gamma_bits[grp]);
    float scale = 128.0f / (gamma + EPS);
    const float lo = -128.0f + EPS, hi = 128.0f - EPS;
    float4 v = reinterpret_cast<const float4*>(x2 + (size_t)row * D_MODEL)[tid];
    float4 qv;
    qv.x = fminf(hi, fmaxf(lo, v.x * scale));
    qv.y = fminf(hi, fmaxf(lo, v.y * scale));
    qv.z = fminf(hi, fmaxf(lo, v.z * scale));
    qv.w = fminf(hi, fmaxf(lo, v.w * scale));
    reinterpret_cast<float4*>(qx + (size_t)row * D_MODEL)[tid] = qv;
    float s = qv.x + qv.y + qv.z + qv.w;
    float q = qv.x*qv.x + qv.y*qv.y + qv.z*qv.z + qv.w*qv.w;
    #pragma unroll
    for (int off = 32; off > 0; off >>= 1) { s += __shfl_down(s, off); q += __shfl_down(q, off); }
    __shared__ float rs[4], rq[4], smean, srstd;
    if ((tid & 63) == 0) { rs[tid >> 6] = s; rq[tid >> 6] = q; }
    __syncthreads();
    if (tid == 0) {
        float ts = rs[0]+rs[1]+rs[2]+rs[3], tq = rq[0]+rq[1]+rq[2]+rq[3];
        float mean = ts * (1.0f / D_MODEL);
        smean = mean;
        srstd = rsqrtf(tq * (1.0f / D_MODEL) - mean*mean + EPS);
    }
    __syncthreads();
    float mean = smean, rstd = srstd;
    float4 gg = reinterpret_cast<const float4*>(g)[tid];
    float4 bb = reinterpret_cast<const float4*>(b)[tid];
    ushort4 o;
    o.x = f2bf((qv.x-mean)*rstd*gg.x + bb.x);
    o.y = f2bf((qv.y-mean)*rstd*gg.y + bb.y);
    o.z = f2bf((qv.z-mean)*rstd*gg.z + bb.z);
    o.w = f2bf((qv.w-mean)*rstd*gg.w + bb.w);
    reinterpret_cast<ushort4*>(u + (size_t)row * D_MODEL)[tid] = o;
}

// -------------- depthwise causal conv + SiLU (bf16 in/out) ------------------
__global__ __launch_bounds__(256) void conv_silu_kernel(const unsigned short* __restrict__ xz,
                                                        const float* __restrict__ conv_w,
                                                        const float* __restrict__ conv_b,
                                                        unsigned short* __restrict__ xcb) {
    int c = blockIdx.x * 256 + threadIdx.x;   // 0..2047
    int m = blockIdx.y;                        // 0..4095
    int b = m >> 11, l = m & (SEQ - 1);
    float4 w4 = reinterpret_cast<const float4*>(conv_w)[c];
    float wv[4] = {w4.x, w4.y, w4.z, w4.w};
    float s = conv_b[c];
    const unsigned short* base = xz + ((size_t)b * SEQ) * 4096 + c;
    #pragma unroll
    for (int k = 0; k < 4; ++k) {
        int ll = l - 3 + k;
        if (ll >= 0) s += bf2f(base[(size_t)ll * 4096]) * wv[k];
    }
    float sig = 1.0f / (1.0f + __expf(-s));
    xcb[(size_t)m * D_INNER + c] = f2bf(s * sig);
}

// ----------------------------- chunked selective scan ------------------------
// dA[s]=exp(dt*a[s]); when a[s]==a[0]*(s+1) (mamba default A), use E^(s+1)
// via log-depth products: dA[s] = dA[s>>1]*dA[(s-1)>>1]  -> 1 exp + 15 mul/step.
__device__ __forceinline__ void make_dA(float dA[D_STATE], float dtv,
                                        const float* a, bool pw) {
    if (pw) {
        dA[0] = __expf(dtv * a[0]);
        #pragma unroll
        for (int s = 1; s < D_STATE; ++s) dA[s] = dA[s>>1] * dA[(s-1)>>1];
    } else {
        #pragma unroll
        for (int s = 0; s < D_STATE; ++s) dA[s] = __expf(dtv * a[s]);
    }
}

__global__ __launch_bounds__(256) void scan_partial_kernel(
    const float* __restrict__ dt, const unsigned short* __restrict__ xcb,
    const float* __restrict__ xdbl, const float* __restrict__ A_log,
    float* __restrict__ Lbuf, float* __restrict__ Sbuf)
{
    int gtid = blockIdx.x * 256 + threadIdx.x;
    int ch = gtid & (NCH - 1);
    int c  = gtid >> 12;                      // chunk 0..63
    int b = ch >> 11, d = ch & (D_INNER - 1);
    float a[D_STATE], h[D_STATE];
    bool pw = true;
    #pragma unroll
    for (int s = 0; s < D_STATE; ++s) {
        a[s] = -__expf(A_log[(size_t)d * D_STATE + s]);
        h[s] = 0.0f;
    }
    #pragma unroll
    for (int s = 1; s < D_STATE; ++s)
        pw = pw && (fabsf(a[s] - a[0]*(float)(s+1)) <= 1e-3f * fabsf(a[s]));

    size_t m0 = (size_t)b * SEQ + (size_t)c * CLEN;
    float Ssum = 0.0f;

    float dt_n = dt[m0 * D_INNER + d];
    float x_n  = bf2f(xcb[m0 * D_INNER + d]);
    float4 B_n[4];
    {
        const float* xd = xdbl + m0 * 96;
        #pragma unroll
        for (int i = 0; i < 4; ++i)
            B_n[i] = *reinterpret_cast<const float4*>(xd + DT_RANK + 4*i);
    }

    for (int l = 0; l < CLEN; ++l) {
        float dtv = dt_n, xv = x_n;
        float Bc[D_STATE];
        #pragma unroll
        for (int i = 0; i < 4; ++i) {
            Bc[4*i+0] = B_n[i].x; Bc[4*i+1] = B_n[i].y; Bc[4*i+2] = B_n[i].z; Bc[4*i+3] = B_n[i].w;
        }
        if (l + 1 < CLEN) {
            size_t m1 = m0 + l + 1;
            dt_n = dt[m1 * D_INNER + d];
            x_n  = bf2f(xcb[m1 * D_INNER + d]);
            const float* xd = xdbl + m1 * 96;
            #pragma unroll
            for (int i = 0; i < 4; ++i)
                B_n[i] = *reinterpret_cast<const float4*>(xd + DT_RANK + 4*i);
        }
        Ssum += dtv;
        float dx = dtv * xv;
        float dA[D_STATE];
        make_dA(dA, dtv, a, pw);
        #pragma unroll
        for (int s = 0; s < D_STATE; ++s)
            h[s] = h[s] * dA[s] + dx * Bc[s];
    }
    float4* Lp = reinterpret_cast<float4*>(Lbuf + (size_t)c * (NCH * D_STATE) + (size_t)ch * D_STATE);
    Lp[0] = make_float4(h[0], h[1], h[2], h[3]);
    Lp[1] = make_float4(h[4], h[5], h[6], h[7]);
    Lp[2] = make_float4(h[8], h[9], h[10], h[11]);
    Lp[3] = make_float4(h[12], h[13], h[14], h[15]);
    Sbuf[(size_t)c * NCH + ch] = Ssum;
}

__global__ __launch_bounds__(256) void scan_combine_kernel(
    float* __restrict__ LH, const float* __restrict__ Sbuf,
    const float* __restrict__ A_log)
{
    int gtid = blockIdx.x * 256 + threadIdx.x;
    int s = gtid & (D_STATE - 1);
    int ch = gtid >> 4;
    int d = ch & (D_INNER - 1);
    float a = -__expf(A_log[(size_t)d * D_STATE + s]);
    float h = 0.0f;
    #pragma unroll 4
    for (int c = 0; c < NCHUNK; ++c) {
        size_t idx = (size_t)c * (NCH * D_STATE) + (size_t)ch * D_STATE + s;
        float loc = LH[idx];
        LH[idx] = h;
        float P = __expf(a * Sbuf[(size_t)c * NCH + ch]);
        h = h * P + loc;
    }
}

__global__ __launch_bounds__(256) void scan_final_kernel(
    const float* __restrict__ dt, const unsigned short* __restrict__ xcb,
    const unsigned short* __restrict__ xzb, const float* __restrict__ xdbl,
    const float* __restrict__ A_log, const float* __restrict__ D_param,
    const float* __restrict__ Hin, unsigned short* __restrict__ yb)
{
    int gtid = blockIdx.x * 256 + threadIdx.x;
    int ch = gtid & (NCH - 1);
    int c  = gtid >> 12;
    int b = ch >> 11, d = ch & (D_INNER - 1);
    float a[D_STATE], h[D_STATE];
    {
        const float4* Hp = reinterpret_cast<const float4*>(
            Hin + (size_t)c * (NCH * D_STATE) + (size_t)ch * D_STATE);
        float4 h0 = Hp[0], h1 = Hp[1], h2 = Hp[2], h3 = Hp[3];
        h[0]=h0.x; h[1]=h0.y; h[2]=h0.z; h[3]=h0.w;
        h[4]=h1.x; h[5]=h1.y; h[6]=h1.z; h[7]=h1.w;
        h[8]=h2.x; h[9]=h2.y; h[10]=h2.z; h[11]=h2.w;
        h[12]=h3.x; h[13]=h3.y; h[14]=h3.z; h[15]=h3.w;
    }
    bool pw = true;
    #pragma unroll
    for (int s = 0; s < D_STATE; ++s)
        a[s] = -__expf(A_log[(size_t)d * D_STATE + s]);
    #pragma unroll
    for (int s = 1; s < D_STATE; ++s)
        pw = pw && (fabsf(a[s] - a[0]*(float)(s+1)) <= 1e-3f * fabsf(a[s]));
    float Dp = D_param[d];

    size_t m0 = (size_t)b * SEQ + (size_t)c * CLEN;
    float dt_n = dt[m0 * D_INNER + d];
    float x_n  = bf2f(xcb[m0 * D_INNER + d]);
    float z_n  = bf2f(xzb[m0 * 4096 + D_INNER + d]);
    float4 B_n[4], C_n[4];
    {
        const float* xd = xdbl + m0 * 96;
        #pragma unroll
        for (int i = 0; i < 4; ++i) {
            B_n[i] = *reinterpret_cast<const float4*>(xd + DT_RANK + 4*i);
            C_n[i] = *reinterpret_cast<const float4*>(xd + DT_RANK + D_STATE + 4*i);
        }
    }

    for (int l = 0; l < CLEN; ++l) {
        float dtv = dt_n, xv = x_n, zv = z_n;
        float Bc[D_STATE], Cc[D_STATE];
        #pragma unroll
        for (int i = 0; i < 4; ++i) {
            Bc[4*i+0] = B_n[i].x; Bc[4*i+1] = B_n[i].y; Bc[4*i+2] = B_n[i].z; Bc[4*i+3] = B_n[i].w;
            Cc[4*i+0] = C_n[i].x; Cc[4*i+1] = C_n[i].y; Cc[4*i+2] = C_n[i].z; Cc[4*i+3] = C_n[i].w;
        }
        if (l + 1 < CLEN) {
            size_t m1 = m0 + l + 1;
            dt_n = dt[m1 * D_INNER + d];
            x_n  = bf2f(xcb[m1 * D_INNER + d]);
            z_n  = bf2f(xzb[m1 * 4096 + D_INNER + d]);
            const float* xd = xdbl + m1 * 96;
            #pragma unroll
            for (int i = 0; i < 4; ++i) {
                B_n[i] = *reinterpret_cast<const float4*>(xd + DT_RANK + 4*i);
                C_n[i] = *reinterpret_cast<const float4*>(xd + DT_RANK + D_STATE + 4*i);
            }
        }
        float dx = dtv * xv;
        float yv = 0.0f;
        float dA[D_STATE];
        make_dA(dA, dtv, a, pw);
        #pragma unroll
        for (int s = 0; s < D_STATE; ++s) {
            h[s] = h[s] * dA[s] + dx * Bc[s];
            yv += h[s] * Cc[s];
        }
        yv += Dp * xv;
        float sig = 1.0f / (1.0f + __expf(-zv));
        yb[(m0 + l) * D_INNER + d] = f2bf(yv * (zv * sig));
    }
}

// ----------------------------- launch ---------------------------------------
extern "C" void kernel_launch(void* const* d_in, const int* in_sizes, int n_in,
                              void* d_out, int out_size, void* d_ws, size_t ws_size,
                              hipStream_t stream) {
    const float* x         = (const float*)d_in[0];
    const float* ln1_g     = (const float*)d_in[1];
    const float* ln1_b     = (const float*)d_in[2];
    const float* ln2_g     = (const float*)d_in[3];
    const float* ln2_b     = (const float*)d_in[4];
    const float* W1        = (const float*)d_in[5];
    const float* b1        = (const float*)d_in[6];
    const float* W2        = (const float*)d_in[7];
    const float* b2        = (const float*)d_in[8];
    const float* in_proj   = (const float*)d_in[9];
    const float* conv_w    = (const float*)d_in[10];
    const float* conv_b    = (const float*)d_in[11];
    const float* x_proj    = (const float*)d_in[12];
    const float* dt_proj   = (const float*)d_in[13];
    const float* dt_proj_b = (const float*)d_in[14];
    const float* A_log     = (const float*)d_in[15];
    const float* D_param   = (const float*)d_in[16];
    const float* out_proj  = (const float*)d_in[17];
    float* out = (float*)d_out;

    // ---- workspace layout (bytes), ~159 MiB ----
    char* ws = (char*)d_ws;
    float*          f_x2   = (float*)         (ws + 0);          // 16,777,216  x2/qx
    unsigned short* b_xz   = (unsigned short*)(ws + 16777216);   // 33,554,432  bf16 [xs|z]
    float*          f_dt   = (float*)         (ws + 50331648);   // 33,554,432  dt fp32
    float*          f_xdbl = (float*)         (ws + 83886080);   //  1,572,864
    float*          f_L    = (float*)         (ws + 85458944);   // 16,777,216
    float*          f_S    = (float*)         (ws + 102236160);  //  1,048,576
    unsigned int*   f_gamma= (unsigned int*)  (ws + 103284736);  // 64
    unsigned short* b_a1hi = (unsigned short*)(ws + 103284800);  //  8,388,608
    unsigned short* b_a1lo = b_a1hi + 4194304;                   //  8,388,608
    unsigned short* b_y    = b_a1hi;                             //  reuse 16 MB
    unsigned short* b_gated= (unsigned short*)(ws + 120062016);  // 16,777,216
    unsigned short* b_xc   = b_gated;                            //  reuse
    unsigned short* b_u    = (unsigned short*)(ws + 136839232);  //  8,388,608
    unsigned short* b_xdt  = b_u;                                //  reuse 512 KB
    unsigned short* b_w1s  = (unsigned short*)(ws + 145227840);  //  4,194,304
    unsigned short* b_w2s  = (unsigned short*)(ws + 149422144);  //  4,194,304
    unsigned short* b_inpj = (unsigned short*)(ws + 153616448);  //  8,388,608
    unsigned short* b_xpj  = (unsigned short*)(ws + 162005056);  //    393,216
    unsigned short* b_dtpj = (unsigned short*)(ws + 162398272);  //    262,144
    unsigned short* b_outpj= (unsigned short*)(ws + 162660416);  //  4,194,304

    dim3 b256(256);

    // 0. all weight conversions in one launch
    f2bf_all_kernel<<<dim3((F4_C6 + 255)/256), b256, 0, stream>>>(
        W1, W2, in_proj, x_proj, dt_proj, out_proj,
        b_w1s, b_w2s, b_inpj, b_xpj, b_dtpj, b_outpj);

    // 1. LN1 -> hi/lo bf16
    ln_hilo_kernel<<<dim3(NTOK), b256, 0, stream>>>(x, ln1_g, ln1_b, b_a1hi, b_a1lo);
    // 2. gated = clip((hi+lo) @ sign(W1)^T + b1) -> bf16
    mfma_gemm<1, true><<<dim3(16, 32), b256, 0, stream>>>(
        b_a1hi, b_a1lo, b_w1s, nullptr, b_gated, NTOK, D_INNER, D_MODEL, D_MODEL, D_INNER,
        b1, nullptr, 0, nullptr);
    // 3. x2 = gated @ sign(W2)^T + b2 + x -> fp32, fused groupwise absmax
    init_gamma_kernel<<<1, 64, 0, stream>>>(f_gamma);
    mfma_gemm<7, false><<<dim3(8, 32), b256, 0, stream>>>(
        b_gated, nullptr, b_w2s, f_x2, nullptr, NTOK, D_MODEL, D_INNER, D_INNER, D_MODEL,
        b2, x, D_MODEL, f_gamma);
    // 4+5. fused quant (in-place semantics) + LN2 -> qx fp32, u bf16
    quant_ln_kernel<<<dim3(NTOK), b256, 0, stream>>>(f_x2, f_gamma, ln2_g, ln2_b, f_x2, b_u);
    // 6. xz = u @ in_proj^T -> bf16
    mfma_gemm<6, false><<<dim3(32, 32), b256, 0, stream>>>(
        b_u, nullptr, b_inpj, nullptr, b_xz, NTOK, 2*D_INNER, D_MODEL, D_MODEL, 2*D_INNER,
        nullptr, nullptr, 0, nullptr);
    // 7. conv + silu -> bf16 xc
    conv_silu_kernel<<<dim3(D_INNER/256, NTOK), b256, 0, stream>>>(b_xz, conv_w, conv_b, b_xc);
    // 8. x_dbl = xc @ x_proj^T -> fp32 (+ bf16 dt-rank cols)
    mfma_gemm<5, false><<<dim3(1, 32), b256, 0, stream>>>(
        b_xc, nullptr, b_xpj, f_xdbl, b_xdt, NTOK, DT_RANK + 2*D_STATE, D_INNER, D_INNER,
        DT_RANK + 2*D_STATE, nullptr, nullptr, 0, nullptr);
    // 9. dt = softplus(xdt @ dt_proj^T + b) -> fp32
    mfma_gemm<3, false><<<dim3(16, 32), b256, 0, stream>>>(
        b_xdt, nullptr, b_dtpj, f_dt, nullptr, NTOK, D_INNER, DT_RANK, DT_RANK, D_INNER,
        dt_proj_b, nullptr, 0, nullptr);
    // 10. chunked scan
    scan_partial_kernel<<<dim3(NCH*NCHUNK/256), b256, 0, stream>>>(
        f_dt, b_xc, f_xdbl, A_log, f_L, f_S);
    scan_combine_kernel<<<dim3(NCH*D_STATE/256), b256, 0, stream>>>(f_L, f_S, A_log);
    scan_final_kernel<<<dim3(NCH*NCHUNK/256), b256, 0, stream>>>(
        f_dt, b_xc, b_xz, f_xdbl, A_log, D_param, f_L, b_y);
    // 11. out = y @ out_proj^T + qx -> fp32
    mfma_gemm<4, false><<<dim3(8, 32), b256, 0, stream>>>(
        b_y, nullptr, b_outpj, out, nullptr, NTOK, D_MODEL, D_INNER, D_INNER, D_MODEL,
        nullptr, f_x2, D_MODEL, nullptr);
}

// Round 6
// 478.243 us; speedup vs baseline: 6.2090x; 1.0496x over previous
//
#include <hip/hip_runtime.h>
#include <math.h>

#define D_MODEL 1024
#define D_INNER 2048
#define D_STATE 16
#define DT_RANK 64
#define BSZ 2
#define SEQ 2048
#define NTOK (BSZ*SEQ)     // 4096
#define NCH  (BSZ*D_INNER) // 4096 channels
#define NCHUNK 64
#define CLEN 32            // SEQ / NCHUNK
#define EPS 1e-5f

typedef __attribute__((ext_vector_type(8))) short short8v;
typedef __attribute__((ext_vector_type(4))) float f32x4;

__device__ __forceinline__ float sgnf(float w) {
    return (w > 0.f) ? 1.f : ((w < 0.f) ? -1.f : 0.f);
}
__device__ __forceinline__ unsigned short f2bf(float f) {   // RNE fp32->bf16
    unsigned int x = __float_as_uint(f);
    x += 0x7fffu + ((x >> 16) & 1u);
    return (unsigned short)(x >> 16);
}
__device__ __forceinline__ float bf2f(unsigned short u) {
    return __uint_as_float(((unsigned int)u) << 16);
}
__device__ __forceinline__ void stage16(const unsigned short* g, unsigned short* l) {
    __builtin_amdgcn_global_load_lds(
        (const __attribute__((address_space(1))) unsigned int*)g,
        (__attribute__((address_space(3))) unsigned int*)l, 16, 0, 0);
}

// ------------------- merged weight conversion (6 tensors, 1 launch) ---------
#define F4_C1   524288
#define F4_C2   1048576
#define F4_C3   2097152
#define F4_C4   2146304
#define F4_C5   2179072
#define F4_C6   2703360
__global__ __launch_bounds__(256) void f2bf_all_kernel(
    const float* __restrict__ W1, const float* __restrict__ W2,
    const float* __restrict__ inpj, const float* __restrict__ xpj,
    const float* __restrict__ dtpj, const float* __restrict__ outpj,
    unsigned short* __restrict__ o_w1, unsigned short* __restrict__ o_w2,
    unsigned short* __restrict__ o_in, unsigned short* __restrict__ o_xp,
    unsigned short* __restrict__ o_dt, unsigned short* __restrict__ o_out,
    unsigned int* __restrict__ gma)
{
    int i = blockIdx.x * 256 + threadIdx.x;
    if (blockIdx.x == 0 && threadIdx.x < 4) gma[threadIdx.x] = 0u;  // gamma init
    if (i >= F4_C6) return;
    const float* src; unsigned short* dst; int off; bool sign = false;
    if (i < F4_C1)      { src = W1;   dst = o_w1;  off = i;          sign = true; }
    else if (i < F4_C2) { src = W2;   dst = o_w2;  off = i - F4_C1;  sign = true; }
    else if (i < F4_C3) { src = inpj; dst = o_in;  off = i - F4_C2; }
    else if (i < F4_C4) { src = xpj;  dst = o_xp;  off = i - F4_C3; }
    else if (i < F4_C5) { src = dtpj; dst = o_dt;  off = i - F4_C4; }
    else                { src = outpj;dst = o_out; off = i - F4_C5; }
    float4 v = reinterpret_cast<const float4*>(src)[off];
    if (sign) { v.x = sgnf(v.x); v.y = sgnf(v.y); v.z = sgnf(v.z); v.w = sgnf(v.w); }
    ushort4 o;
    o.x = f2bf(v.x); o.y = f2bf(v.y); o.z = f2bf(v.z); o.w = f2bf(v.w);
    reinterpret_cast<ushort4*>(dst)[off] = o;
}

// ----------------------------- LN1 -> hi/lo bf16 ----------------------------
__global__ __launch_bounds__(256) void ln_hilo_kernel(const float* __restrict__ x,
                                                      const float* __restrict__ g,
                                                      const float* __restrict__ b,
                                                      unsigned short* __restrict__ hi,
                                                      unsigned short* __restrict__ lo) {
    int row = blockIdx.x, tid = threadIdx.x;
    float4 v = reinterpret_cast<const float4*>(x + (size_t)row * D_MODEL)[tid];
    float s = v.x + v.y + v.z + v.w;
    float q = v.x*v.x + v.y*v.y + v.z*v.z + v.w*v.w;
    #pragma unroll
    for (int off = 32; off > 0; off >>= 1) { s += __shfl_down(s, off); q += __shfl_down(q, off); }
    __shared__ float rs[4], rq[4], smean, srstd;
    if ((tid & 63) == 0) { rs[tid >> 6] = s; rq[tid >> 6] = q; }
    __syncthreads();
    if (tid == 0) {
        float ts = rs[0]+rs[1]+rs[2]+rs[3], tq = rq[0]+rq[1]+rq[2]+rq[3];
        float mean = ts * (1.0f / D_MODEL);
        smean = mean;
        srstd = rsqrtf(tq * (1.0f / D_MODEL) - mean*mean + EPS);
    }
    __syncthreads();
    float mean = smean, rstd = srstd;
    float4 gg = reinterpret_cast<const float4*>(g)[tid];
    float4 bb = reinterpret_cast<const float4*>(b)[tid];
    float o[4];
    o[0] = (v.x-mean)*rstd*gg.x + bb.x; o[1] = (v.y-mean)*rstd*gg.y + bb.y;
    o[2] = (v.z-mean)*rstd*gg.z + bb.z; o[3] = (v.w-mean)*rstd*gg.w + bb.w;
    ushort4 h4, l4;
    h4.x = f2bf(o[0]); l4.x = f2bf(o[0] - bf2f(h4.x));
    h4.y = f2bf(o[1]); l4.y = f2bf(o[1] - bf2f(h4.y));
    h4.z = f2bf(o[2]); l4.z = f2bf(o[2] - bf2f(h4.z));
    h4.w = f2bf(o[3]); l4.w = f2bf(o[3] - bf2f(h4.w));
    reinterpret_cast<ushort4*>(hi + (size_t)row * D_MODEL)[tid] = h4;
    reinterpret_cast<ushort4*>(lo + (size_t)row * D_MODEL)[tid] = l4;
}

// ----------------------------- MFMA GEMM ------------------------------------
// C[M,N](+epilogue) = A[M,K]bf16 @ B[N,K]bf16^T   (m97 structure, BM=128)
// BN in {128, 64}. KSPLIT: gridDim.z slices of length ksl; C += z*M*sC.
// EP: 0 C=fp32 | 1 Cb=bf16 clip(v+bias) | 3 C=fp32 softplus(v+bias)
//     4 C=fp32 v+addx | 6 Cb=bf16 v | 7 C=fp32 v+bias+addx, absmax->gma
template<int EP, bool DUALA, int BN, bool KSPLIT>
__global__ __launch_bounds__(256) void mfma_gemm(
    const unsigned short* __restrict__ A, const unsigned short* __restrict__ A2,
    const unsigned short* __restrict__ B, float* __restrict__ C,
    unsigned short* __restrict__ Cb,
    int M, int N, int K, int sA, int sC,
    const float* __restrict__ bias, const float* __restrict__ addx, int sAdd,
    unsigned int* __restrict__ gma, int ksl)
{
    constexpr int NF = BN / 32;            // N-frags per wave (wave N-span BN/2)
    __shared__ __align__(16) unsigned short As[128*32];
    __shared__ __align__(16) unsigned short As2[DUALA ? 128*32 : 8];
    __shared__ __align__(16) unsigned short Bs[BN*32];
    __shared__ float redmax[4];
    const int tid = threadIdx.x;
    const int lane = tid & 63;
    const int w = tid >> 6;
    const int wm = w >> 1, wn = w & 1;
    const int row0 = blockIdx.y * 128, col0 = blockIdx.x * BN;
    const int srow = lane >> 2;            // 0..15
    const int scol = (lane & 3) * 8;       // 0,8,16,24

    int k_begin = 0, k_end = K;
    if (KSPLIT) {
        int z = blockIdx.z;
        k_begin = z * ksl; k_end = k_begin + ksl;
        C += (size_t)z * M * sC;
    }

    f32x4 acc[4][NF];
    #pragma unroll
    for (int m = 0; m < 4; ++m)
        #pragma unroll
        for (int n = 0; n < NF; ++n)
            acc[m][n] = (f32x4){0.f, 0.f, 0.f, 0.f};

    for (int k0 = k_begin; k0 < k_end; k0 += 32) {
        #pragma unroll
        for (int i = 0; i < 2; ++i) {
            const int rbase = w * 32 + i * 16;               // wave-uniform
            stage16(A + (size_t)(row0 + rbase + srow) * sA + k0 + scol, &As[rbase * 32]);
            if (DUALA)
                stage16(A2 + (size_t)(row0 + rbase + srow) * sA + k0 + scol, &As2[rbase * 32]);
        }
        #pragma unroll
        for (int i = 0; i < BN/64; ++i) {
            const int rbase = (BN == 128) ? (w * 32 + i * 16) : (w * 16);
            if (col0 + rbase < N)                            // N%16==0 in all uses
                stage16(B + (size_t)(col0 + rbase + srow) * K + k0 + scol, &Bs[rbase * 32]);
        }
        __syncthreads();                                     // drains vmcnt before LDS reads

        short8v af[4], bfr[NF], af2[4];
        const int fr = lane & 15, kg = (lane >> 4) * 8;
        #pragma unroll
        for (int m = 0; m < 4; ++m)
            af[m] = *reinterpret_cast<const short8v*>(&As[(wm*64 + m*16 + fr) * 32 + kg]);
        if (DUALA) {
            #pragma unroll
            for (int m = 0; m < 4; ++m)
                af2[m] = *reinterpret_cast<const short8v*>(&As2[(wm*64 + m*16 + fr) * 32 + kg]);
        }
        #pragma unroll
        for (int n = 0; n < NF; ++n)
            bfr[n] = *reinterpret_cast<const short8v*>(&Bs[(wn*(BN/2) + n*16 + fr) * 32 + kg]);

        #pragma unroll
        for (int m = 0; m < 4; ++m)
            #pragma unroll
            for (int n = 0; n < NF; ++n) {
                acc[m][n] = __builtin_amdgcn_mfma_f32_16x16x32_bf16(af[m], bfr[n], acc[m][n], 0, 0, 0);
                if (DUALA)
                    acc[m][n] = __builtin_amdgcn_mfma_f32_16x16x32_bf16(af2[m], bfr[n], acc[m][n], 0, 0, 0);
            }
        __syncthreads();
    }

    // C/D layout (m89-verified): col = lane&15, row = (lane>>4)*4 + reg
    const int fc = lane & 15, r4 = (lane >> 4) * 4;
    float lmax = 0.0f;
    #pragma unroll
    for (int m = 0; m < 4; ++m) {
        const int grb = row0 + wm*64 + m*16 + r4;
        #pragma unroll
        for (int n = 0; n < NF; ++n) {
            const int gc = col0 + wn*(BN/2) + n*16 + fc;
            if (gc >= N) continue;
            #pragma unroll
            for (int j = 0; j < 4; ++j) {
                const int r = grb + j;
                float v = acc[m][n][j];
                if (EP == 0) {
                    C[(size_t)r*sC + gc] = v;
                } else if (EP == 1) {
                    v += bias[gc];
                    v = fminf(1.0f, fmaxf(-1.0f, v));
                    Cb[(size_t)r*sC + gc] = f2bf(v);
                } else if (EP == 3) {
                    float t = v + bias[gc];
                    C[(size_t)r*sC + gc] = fmaxf(t, 0.0f) + log1pf(__expf(-fabsf(t)));
                } else if (EP == 4) {
                    C[(size_t)r*sC + gc] = v + addx[(size_t)r*sAdd + gc];
                } else if (EP == 6) {
                    Cb[(size_t)r*sC + gc] = f2bf(v);
                } else { // EP == 7
                    v += bias[gc] + addx[(size_t)r*sAdd + gc];
                    C[(size_t)r*sC + gc] = v;
                    lmax = fmaxf(lmax, fabsf(v));
                }
            }
        }
    }
    if (EP == 7) {
        #pragma unroll
        for (int off = 32; off > 0; off >>= 1) lmax = fmaxf(lmax, __shfl_down(lmax, off));
        if (lane == 0) redmax[w] = lmax;
        __syncthreads();
        if (tid == 0) {
            float t = fmaxf(fmaxf(redmax[0], redmax[1]), fmaxf(redmax[2], redmax[3]));
            int g = (row0 & (SEQ - 1)) >> 9;   // 128-row tile lies in one 512-group
            atomicMax(gma + g, __float_as_uint(t));
        }
    }
}

// ------------- x_proj split-K combine: xdbl = sum partials; emit bf16 dt ----
__global__ __launch_bounds__(256) void xproj_combine_kernel(
    const float* __restrict__ part,     // [4][NTOK][96]
    float* __restrict__ xdbl,           // [NTOK][96]
    unsigned short* __restrict__ xdt)   // [NTOK][64]
{
    int i = blockIdx.x * 256 + threadIdx.x;          // f4 index, NTOK*24 total
    if (i >= NTOK * 24) return;
    const size_t stride = (size_t)NTOK * 96 / 4;
    float4 v0 = reinterpret_cast<const float4*>(part)[i];
    float4 v1 = reinterpret_cast<const float4*>(part)[i + stride];
    float4 v2 = reinterpret_cast<const float4*>(part)[i + 2*stride];
    float4 v3 = reinterpret_cast<const float4*>(part)[i + 3*stride];
    float4 o;
    o.x = (v0.x + v1.x) + (v2.x + v3.x);
    o.y = (v0.y + v1.y) + (v2.y + v3.y);
    o.z = (v0.z + v1.z) + (v2.z + v3.z);
    o.w = (v0.w + v1.w) + (v2.w + v3.w);
    reinterpret_cast<float4*>(xdbl)[i] = o;
    int row = i / 24, c4 = i % 24;
    if (c4 < 16) {                                    // cols 0..63 -> bf16 dt input
        ushort4 u;
        u.x = f2bf(o.x); u.y = f2bf(o.y); u.z = f2bf(o.z); u.w = f2bf(o.w);
        reinterpret_cast<ushort4*>(xdt + (size_t)row * 64)[c4] = u;
    }
}

// ------------------- fused quant + LN2 (qx fp32 + u bf16) -------------------
__global__ __launch_bounds__(256) void quant_ln_kernel(
    const float* __restrict__ x2, const unsigned int* __restrict__ gamma_bits,
    const float* __restrict__ g, const float* __restrict__ b,
    float* __restrict__ qx, unsigned short* __restrict__ u)
{
    int row = blockIdx.x, tid = threadIdx.x;
    int grp = (row & (SEQ - 1)) >> 9;
    float gamma = __uint_as_float(gamma_bits[grp]);
    float scale = 128.0f / (gamma + EPS);
    const float lo = -128.0f + EPS, hi = 128.0f - EPS;
    float4 v = reinterpret_cast<const float4*>(x2 + (size_t)row * D_MODEL)[tid];
    float4 qv;
    qv.x = fminf(hi, fmaxf(lo, v.x * scale));
    qv.y = fminf(hi, fmaxf(lo, v.y * scale));
    qv.z = fminf(hi, fmaxf(lo, v.z * scale));
    qv.w = fminf(hi, fmaxf(lo, v.w * scale));
    reinterpret_cast<float4*>(qx + (size_t)row * D_MODEL)[tid] = qv;
    float s = qv.x + qv.y + qv.z + qv.w;
    float q = qv.x*qv.x + qv.y*qv.y + qv.z*qv.z + qv.w*qv.w;
    #pragma unroll
    for (int off = 32; off > 0; off >>= 1) { s += __shfl_down(s, off); q += __shfl_down(q, off); }
    __shared__ float rs[4], rq[4], smean, srstd;
    if ((tid & 63) == 0) { rs[tid >> 6] = s; rq[tid >> 6] = q; }
    __syncthreads();
    if (tid == 0) {
        float ts = rs[0]+rs[1]+rs[2]+rs[3], tq = rq[0]+rq[1]+rq[2]+rq[3];
        float mean = ts * (1.0f / D_MODEL);
        smean = mean;
        srstd = rsqrtf(tq * (1.0f / D_MODEL) - mean*mean + EPS);
    }
    __syncthreads();
    float mean = smean, rstd = srstd;
    float4 gg = reinterpret_cast<const float4*>(g)[tid];
    float4 bb = reinterpret_cast<const float4*>(b)[tid];
    ushort4 o;
    o.x = f2bf((qv.x-mean)*rstd*gg.x + bb.x);
    o.y = f2bf((qv.y-mean)*rstd*gg.y + bb.y);
    o.z = f2bf((qv.z-mean)*rstd*gg.z + bb.z);
    o.w = f2bf((qv.w-mean)*rstd*gg.w + bb.w);
    reinterpret_cast<ushort4*>(u + (size_t)row * D_MODEL)[tid] = o;
}

// -------------- depthwise causal conv + SiLU (bf16 in/out) ------------------
__global__ __launch_bounds__(256) void conv_silu_kernel(const unsigned short* __restrict__ xz,
                                                        const float* __restrict__ conv_w,
                                                        const float* __restrict__ conv_b,
                                                        unsigned short* __restrict__ xcb) {
    int c = blockIdx.x * 256 + threadIdx.x;   // 0..2047
    int m = blockIdx.y;                        // 0..4095
    int b = m >> 11, l = m & (SEQ - 1);
    float4 w4 = reinterpret_cast<const float4*>(conv_w)[c];
    float wv[4] = {w4.x, w4.y, w4.z, w4.w};
    float s = conv_b[c];
    const unsigned short* base = xz + ((size_t)b * SEQ) * 4096 + c;
    #pragma unroll
    for (int k = 0; k < 4; ++k) {
        int ll = l - 3 + k;
        if (ll >= 0) s += bf2f(base[(size_t)ll * 4096]) * wv[k];
    }
    float sig = 1.0f / (1.0f + __expf(-s));
    xcb[(size_t)m * D_INNER + c] = f2bf(s * sig);
}

// ----------------------------- chunked selective scan ------------------------
__device__ __forceinline__ void make_dA(float dA[D_STATE], float dtv,
                                        const float* a, bool pw) {
    if (pw) {
        dA[0] = __expf(dtv * a[0]);
        #pragma unroll
        for (int s = 1; s < D_STATE; ++s) dA[s] = dA[s>>1] * dA[(s-1)>>1];
    } else {
        #pragma unroll
        for (int s = 0; s < D_STATE; ++s) dA[s] = __expf(dtv * a[s]);
    }
}

__global__ __launch_bounds__(256) void scan_partial_kernel(
    const float* __restrict__ dt, const unsigned short* __restrict__ xcb,
    const float* __restrict__ xdbl, const float* __restrict__ A_log,
    float* __restrict__ Lbuf, float* __restrict__ Sbuf)
{
    int gtid = blockIdx.x * 256 + threadIdx.x;
    int ch = gtid & (NCH - 1);
    int c  = gtid >> 12;                      // chunk 0..63
    int b = ch >> 11, d = ch & (D_INNER - 1);
    float a[D_STATE], h[D_STATE];
    bool pw = true;
    #pragma unroll
    for (int s = 0; s < D_STATE; ++s) {
        a[s] = -__expf(A_log[(size_t)d * D_STATE + s]);
        h[s] = 0.0f;
    }
    #pragma unroll
    for (int s = 1; s < D_STATE; ++s)
        pw = pw && (fabsf(a[s] - a[0]*(float)(s+1)) <= 1e-3f * fabsf(a[s]));

    size_t m0 = (size_t)b * SEQ + (size_t)c * CLEN;
    float Ssum = 0.0f;

    float dt_n = dt[m0 * D_INNER + d];
    float x_n  = bf2f(xcb[m0 * D_INNER + d]);
    float4 B_n[4];
    {
        const float* xd = xdbl + m0 * 96;
        #pragma unroll
        for (int i = 0; i < 4; ++i)
            B_n[i] = *reinterpret_cast<const float4*>(xd + DT_RANK + 4*i);
    }

    for (int l = 0; l < CLEN; ++l) {
        float dtv = dt_n, xv = x_n;
        float Bc[D_STATE];
        #pragma unroll
        for (int i = 0; i < 4; ++i) {
            Bc[4*i+0] = B_n[i].x; Bc[4*i+1] = B_n[i].y; Bc[4*i+2] = B_n[i].z; Bc[4*i+3] = B_n[i].w;
        }
        if (l + 1 < CLEN) {
            size_t m1 = m0 + l + 1;
            dt_n = dt[m1 * D_INNER + d];
            x_n  = bf2f(xcb[m1 * D_INNER + d]);
            const float* xd = xdbl + m1 * 96;
            #pragma unroll
            for (int i = 0; i < 4; ++i)
                B_n[i] = *reinterpret_cast<const float4*>(xd + DT_RANK + 4*i);
        }
        Ssum += dtv;
        float dx = dtv * xv;
        float dA[D_STATE];
        make_dA(dA, dtv, a, pw);
        #pragma unroll
        for (int s = 0; s < D_STATE; ++s)
            h[s] = h[s] * dA[s] + dx * Bc[s];
    }
    float4* Lp = reinterpret_cast<float4*>(Lbuf + (size_t)c * (NCH * D_STATE) + (size_t)ch * D_STATE);
    Lp[0] = make_float4(h[0], h[1], h[2], h[3]);
    Lp[1] = make_float4(h[4], h[5], h[6], h[7]);
    Lp[2] = make_float4(h[8], h[9], h[10], h[11]);
    Lp[3] = make_float4(h[12], h[13], h[14], h[15]);
    Sbuf[(size_t)c * NCH + ch] = Ssum;
}

__global__ __launch_bounds__(256) void scan_combine_kernel(
    float* __restrict__ LH, const float* __restrict__ Sbuf,
    const float* __restrict__ A_log)
{
    int gtid = blockIdx.x * 256 + threadIdx.x;
    int s = gtid & (D_STATE - 1);
    int ch = gtid >> 4;
    int d = ch & (D_INNER - 1);
    float a = -__expf(A_log[(size_t)d * D_STATE + s]);
    float h = 0.0f;
    #pragma unroll 4
    for (int c = 0; c < NCHUNK; ++c) {
        size_t idx = (size_t)c * (NCH * D_STATE) + (size_t)ch * D_STATE + s;
        float loc = LH[idx];
        LH[idx] = h;
        float P = __expf(a * Sbuf[(size_t)c * NCH + ch]);
        h = h * P + loc;
    }
}

__global__ __launch_bounds__(256) void scan_final_kernel(
    const float* __restrict__ dt, const unsigned short* __restrict__ xcb,
    const unsigned short* __restrict__ xzb, const float* __restrict__ xdbl,
    const float* __restrict__ A_log, const float* __restrict__ D_param,
    const float* __restrict__ Hin, unsigned short* __restrict__ yb)
{
    int gtid = blockIdx.x * 256 + threadIdx.x;
    int ch = gtid & (NCH - 1);
    int c  = gtid >> 12;
    int b = ch >> 11, d = ch & (D_INNER - 1);
    float a[D_STATE], h[D_STATE];
    {
        const float4* Hp = reinterpret_cast<const float4*>(
            Hin + (size_t)c * (NCH * D_STATE) + (size_t)ch * D_STATE);
        float4 h0 = Hp[0], h1 = Hp[1], h2 = Hp[2], h3 = Hp[3];
        h[0]=h0.x; h[1]=h0.y; h[2]=h0.z; h[3]=h0.w;
        h[4]=h1.x; h[5]=h1.y; h[6]=h1.z; h[7]=h1.w;
        h[8]=h2.x; h[9]=h2.y; h[10]=h2.z; h[11]=h2.w;
        h[12]=h3.x; h[13]=h3.y; h[14]=h3.z; h[15]=h3.w;
    }
    bool pw = true;
    #pragma unroll
    for (int s = 0; s < D_STATE; ++s)
        a[s] = -__expf(A_log[(size_t)d * D_STATE + s]);
    #pragma unroll
    for (int s = 1; s < D_STATE; ++s)
        pw = pw && (fabsf(a[s] - a[0]*(float)(s+1)) <= 1e-3f * fabsf(a[s]));
    float Dp = D_param[d];

    size_t m0 = (size_t)b * SEQ + (size_t)c * CLEN;
    float dt_n = dt[m0 * D_INNER + d];
    float x_n  = bf2f(xcb[m0 * D_INNER + d]);
    float z_n  = bf2f(xzb[m0 * 4096 + D_INNER + d]);
    float4 B_n[4], C_n[4];
    {
        const float* xd = xdbl + m0 * 96;
        #pragma unroll
        for (int i = 0; i < 4; ++i) {
            B_n[i] = *reinterpret_cast<const float4*>(xd + DT_RANK + 4*i);
            C_n[i] = *reinterpret_cast<const float4*>(xd + DT_RANK + D_STATE + 4*i);
        }
    }

    for (int l = 0; l < CLEN; ++l) {
        float dtv = dt_n, xv = x_n, zv = z_n;
        float Bc[D_STATE], Cc[D_STATE];
        #pragma unroll
        for (int i = 0; i < 4; ++i) {
            Bc[4*i+0] = B_n[i].x; Bc[4*i+1] = B_n[i].y; Bc[4*i+2] = B_n[i].z; Bc[4*i+3] = B_n[i].w;
            Cc[4*i+0] = C_n[i].x; Cc[4*i+1] = C_n[i].y; Cc[4*i+2] = C_n[i].z; Cc[4*i+3] = C_n[i].w;
        }
        if (l + 1 < CLEN) {
            size_t m1 = m0 + l + 1;
            dt_n = dt[m1 * D_INNER + d];
            x_n  = bf2f(xcb[m1 * D_INNER + d]);
            z_n  = bf2f(xzb[m1 * 4096 + D_INNER + d]);
            const float* xd = xdbl + m1 * 96;
            #pragma unroll
            for (int i = 0; i < 4; ++i) {
                B_n[i] = *reinterpret_cast<const float4*>(xd + DT_RANK + 4*i);
                C_n[i] = *reinterpret_cast<const float4*>(xd + DT_RANK + D_STATE + 4*i);
            }
        }
        float dx = dtv * xv;
        float yv = 0.0f;
        float dA[D_STATE];
        make_dA(dA, dtv, a, pw);
        #pragma unroll
        for (int s = 0; s < D_STATE; ++s) {
            h[s] = h[s] * dA[s] + dx * Bc[s];
            yv += h[s] * Cc[s];
        }
        yv += Dp * xv;
        float sig = 1.0f / (1.0f + __expf(-zv));
        yb[(m0 + l) * D_INNER + d] = f2bf(yv * (zv * sig));
    }
}

// ----------------------------- launch ---------------------------------------
extern "C" void kernel_launch(void* const* d_in, const int* in_sizes, int n_in,
                              void* d_out, int out_size, void* d_ws, size_t ws_size,
                              hipStream_t stream) {
    const float* x         = (const float*)d_in[0];
    const float* ln1_g     = (const float*)d_in[1];
    const float* ln1_b     = (const float*)d_in[2];
    const float* ln2_g     = (const float*)d_in[3];
    const float* ln2_b     = (const float*)d_in[4];
    const float* W1        = (const float*)d_in[5];
    const float* b1        = (const float*)d_in[6];
    const float* W2        = (const float*)d_in[7];
    const float* b2        = (const float*)d_in[8];
    const float* in_proj   = (const float*)d_in[9];
    const float* conv_w    = (const float*)d_in[10];
    const float* conv_b    = (const float*)d_in[11];
    const float* x_proj    = (const float*)d_in[12];
    const float* dt_proj   = (const float*)d_in[13];
    const float* dt_proj_b = (const float*)d_in[14];
    const float* A_log     = (const float*)d_in[15];
    const float* D_param   = (const float*)d_in[16];
    const float* out_proj  = (const float*)d_in[17];
    float* out = (float*)d_out;

    // ---- workspace layout (bytes), ~159 MiB ----
    char* ws = (char*)d_ws;
    float*          f_x2   = (float*)         (ws + 0);          // 16,777,216  x2/qx
    unsigned short* b_xz   = (unsigned short*)(ws + 16777216);   // 33,554,432  bf16 [xs|z]
    float*          f_dt   = (float*)         (ws + 50331648);   // 33,554,432  dt fp32
    float*          f_xdbl = (float*)         (ws + 83886080);   //  1,572,864
    float*          f_L    = (float*)         (ws + 85458944);   // 16,777,216  (scan L; earlier: xproj partials)
    float*          f_xp   = f_L;                                //  6,291,456  alias (consumed before scan)
    float*          f_S    = (float*)         (ws + 102236160);  //  1,048,576
    unsigned int*   f_gamma= (unsigned int*)  (ws + 103284736);  // 64
    unsigned short* b_a1hi = (unsigned short*)(ws + 103284800);  //  8,388,608
    unsigned short* b_a1lo = b_a1hi + 4194304;                   //  8,388,608
    unsigned short* b_y    = b_a1hi;                             //  reuse 16 MB
    unsigned short* b_gated= (unsigned short*)(ws + 120062016);  // 16,777,216
    unsigned short* b_xc   = b_gated;                            //  reuse
    unsigned short* b_u    = (unsigned short*)(ws + 136839232);  //  8,388,608
    unsigned short* b_xdt  = b_u;                                //  reuse 512 KB
    unsigned short* b_w1s  = (unsigned short*)(ws + 145227840);  //  4,194,304
    unsigned short* b_w2s  = (unsigned short*)(ws + 149422144);  //  4,194,304
    unsigned short* b_inpj = (unsigned short*)(ws + 153616448);  //  8,388,608
    unsigned short* b_xpj  = (unsigned short*)(ws + 162005056);  //    393,216
    unsigned short* b_dtpj = (unsigned short*)(ws + 162398272);  //    262,144
    unsigned short* b_outpj= (unsigned short*)(ws + 162660416);  //  4,194,304

    dim3 b256(256);

    // 0. all weight conversions (+ gamma init) in one launch
    f2bf_all_kernel<<<dim3((F4_C6 + 255)/256), b256, 0, stream>>>(
        W1, W2, in_proj, x_proj, dt_proj, out_proj,
        b_w1s, b_w2s, b_inpj, b_xpj, b_dtpj, b_outpj, f_gamma);

    // 1. LN1 -> hi/lo bf16
    ln_hilo_kernel<<<dim3(NTOK), b256, 0, stream>>>(x, ln1_g, ln1_b, b_a1hi, b_a1lo);
    // 2. gated = clip((hi+lo) @ sign(W1)^T + b1) -> bf16   [BN=64, 1024 blocks]
    mfma_gemm<1, true, 64, false><<<dim3(32, 32), b256, 0, stream>>>(
        b_a1hi, b_a1lo, b_w1s, nullptr, b_gated, NTOK, D_INNER, D_MODEL, D_MODEL, D_INNER,
        b1, nullptr, 0, nullptr, 0);
    // 3. x2 = gated @ sign(W2)^T + b2 + x -> fp32, fused absmax [BN=64, 512 blocks]
    mfma_gemm<7, false, 64, false><<<dim3(16, 32), b256, 0, stream>>>(
        b_gated, nullptr, b_w2s, f_x2, nullptr, NTOK, D_MODEL, D_INNER, D_INNER, D_MODEL,
        b2, x, D_MODEL, f_gamma, 0);
    // 4+5. fused quant + LN2 -> qx fp32, u bf16
    quant_ln_kernel<<<dim3(NTOK), b256, 0, stream>>>(f_x2, f_gamma, ln2_g, ln2_b, f_x2, b_u);
    // 6. xz = u @ in_proj^T -> bf16   [BN=128, 1024 blocks]
    mfma_gemm<6, false, 128, false><<<dim3(32, 32), b256, 0, stream>>>(
        b_u, nullptr, b_inpj, nullptr, b_xz, NTOK, 2*D_INNER, D_MODEL, D_MODEL, 2*D_INNER,
        nullptr, nullptr, 0, nullptr, 0);
    // 7. conv + silu -> bf16 xc
    conv_silu_kernel<<<dim3(D_INNER/256, NTOK), b256, 0, stream>>>(b_xz, conv_w, conv_b, b_xc);
    // 8. x_dbl partials = xc @ x_proj^T  [split-K x4, 128 blocks]
    mfma_gemm<0, false, 128, true><<<dim3(1, 32, 4), b256, 0, stream>>>(
        b_xc, nullptr, b_xpj, f_xp, nullptr, NTOK, DT_RANK + 2*D_STATE, D_INNER, D_INNER,
        DT_RANK + 2*D_STATE, nullptr, nullptr, 0, nullptr, 512);
    // 8b. combine partials -> f_xdbl fp32 + b_xdt bf16
    xproj_combine_kernel<<<dim3((NTOK*24 + 255)/256), b256, 0, stream>>>(f_xp, f_xdbl, b_xdt);
    // 9. dt = softplus(xdt @ dt_proj^T + b) -> fp32  [BN=64, 1024 blocks]
    mfma_gemm<3, false, 64, false><<<dim3(32, 32), b256, 0, stream>>>(
        b_xdt, nullptr, b_dtpj, f_dt, nullptr, NTOK, D_INNER, DT_RANK, DT_RANK, D_INNER,
        dt_proj_b, nullptr, 0, nullptr, 0);
    // 10. chunked scan
    scan_partial_kernel<<<dim3(NCH*NCHUNK/256), b256, 0, stream>>>(
        f_dt, b_xc, f_xdbl, A_log, f_L, f_S);
    scan_combine_kernel<<<dim3(NCH*D_STATE/256), b256, 0, stream>>>(f_L, f_S, A_log);
    scan_final_kernel<<<dim3(NCH*NCHUNK/256), b256, 0, stream>>>(
        f_dt, b_xc, b_xz, f_xdbl, A_log, D_param, f_L, b_y);
    // 11. out = y @ out_proj^T + qx -> fp32  [BN=64, 512 blocks]
    mfma_gemm<4, false, 64, false><<<dim3(16, 32), b256, 0, stream>>>(
        b_y, nullptr, b_outpj, out, nullptr, NTOK, D_MODEL, D_INNER, D_INNER, D_MODEL,
        nullptr, f_x2, D_MODEL, nullptr, 0);
}

// Round 8
// 473.063 us; speedup vs baseline: 6.2769x; 1.0109x over previous
//
#include <hip/hip_runtime.h>
#include <math.h>

#define D_MODEL 1024
#define D_INNER 2048
#define D_STATE 16
#define DT_RANK 64
#define BSZ 2
#define SEQ 2048
#define NTOK (BSZ*SEQ)     // 4096
#define NCH  (BSZ*D_INNER) // 4096 channels
#define NCHUNK 64
#define CLEN 32            // SEQ / NCHUNK
#define EPS 1e-5f

typedef __attribute__((ext_vector_type(8))) short short8v;
typedef __attribute__((ext_vector_type(4))) float f32x4;

__device__ __forceinline__ float sgnf(float w) {
    return (w > 0.f) ? 1.f : ((w < 0.f) ? -1.f : 0.f);
}
__device__ __forceinline__ unsigned short f2bf(float f) {   // RNE fp32->bf16
    unsigned int x = __float_as_uint(f);
    x += 0x7fffu + ((x >> 16) & 1u);
    return (unsigned short)(x >> 16);
}
__device__ __forceinline__ float bf2f(unsigned short u) {
    return __uint_as_float(((unsigned int)u) << 16);
}
__device__ __forceinline__ void stage16(const unsigned short* g, unsigned short* l) {
    __builtin_amdgcn_global_load_lds(
        (const __attribute__((address_space(1))) unsigned int*)g,
        (__attribute__((address_space(3))) unsigned int*)l, 16, 0, 0);
}

// ------------------- merged weight conversion (6 tensors, 1 launch) ---------
#define F4_C1   524288
#define F4_C2   1048576
#define F4_C3   2097152
#define F4_C4   2146304
#define F4_C5   2179072
#define F4_C6   2703360
__global__ __launch_bounds__(256) void f2bf_all_kernel(
    const float* __restrict__ W1, const float* __restrict__ W2,
    const float* __restrict__ inpj, const float* __restrict__ xpj,
    const float* __restrict__ dtpj, const float* __restrict__ outpj,
    unsigned short* __restrict__ o_w1, unsigned short* __restrict__ o_w2,
    unsigned short* __restrict__ o_in, unsigned short* __restrict__ o_xp,
    unsigned short* __restrict__ o_dt, unsigned short* __restrict__ o_out,
    unsigned int* __restrict__ gma)
{
    int i = blockIdx.x * 256 + threadIdx.x;
    if (blockIdx.x == 0 && threadIdx.x < 4) gma[threadIdx.x] = 0u;  // gamma init
    if (i >= F4_C6) return;
    const float* src; unsigned short* dst; int off; bool sign = false;
    if (i < F4_C1)      { src = W1;   dst = o_w1;  off = i;          sign = true; }
    else if (i < F4_C2) { src = W2;   dst = o_w2;  off = i - F4_C1;  sign = true; }
    else if (i < F4_C3) { src = inpj; dst = o_in;  off = i - F4_C2; }
    else if (i < F4_C4) { src = xpj;  dst = o_xp;  off = i - F4_C3; }
    else if (i < F4_C5) { src = dtpj; dst = o_dt;  off = i - F4_C4; }
    else                { src = outpj;dst = o_out; off = i - F4_C5; }
    float4 v = reinterpret_cast<const float4*>(src)[off];
    if (sign) { v.x = sgnf(v.x); v.y = sgnf(v.y); v.z = sgnf(v.z); v.w = sgnf(v.w); }
    ushort4 o;
    o.x = f2bf(v.x); o.y = f2bf(v.y); o.z = f2bf(v.z); o.w = f2bf(v.w);
    reinterpret_cast<ushort4*>(dst)[off] = o;
}

// ----------------------------- LN1 -> hi/lo bf16 ----------------------------
__global__ __launch_bounds__(256) void ln_hilo_kernel(const float* __restrict__ x,
                                                      const float* __restrict__ g,
                                                      const float* __restrict__ b,
                                                      unsigned short* __restrict__ hi,
                                                      unsigned short* __restrict__ lo) {
    int row = blockIdx.x, tid = threadIdx.x;
    float4 v = reinterpret_cast<const float4*>(x + (size_t)row * D_MODEL)[tid];
    float s = v.x + v.y + v.z + v.w;
    float q = v.x*v.x + v.y*v.y + v.z*v.z + v.w*v.w;
    #pragma unroll
    for (int off = 32; off > 0; off >>= 1) { s += __shfl_down(s, off); q += __shfl_down(q, off); }
    __shared__ float rs[4], rq[4], smean, srstd;
    if ((tid & 63) == 0) { rs[tid >> 6] = s; rq[tid >> 6] = q; }
    __syncthreads();
    if (tid == 0) {
        float ts = rs[0]+rs[1]+rs[2]+rs[3], tq = rq[0]+rq[1]+rq[2]+rq[3];
        float mean = ts * (1.0f / D_MODEL);
        smean = mean;
        srstd = rsqrtf(tq * (1.0f / D_MODEL) - mean*mean + EPS);
    }
    __syncthreads();
    float mean = smean, rstd = srstd;
    float4 gg = reinterpret_cast<const float4*>(g)[tid];
    float4 bb = reinterpret_cast<const float4*>(b)[tid];
    float o[4];
    o[0] = (v.x-mean)*rstd*gg.x + bb.x; o[1] = (v.y-mean)*rstd*gg.y + bb.y;
    o[2] = (v.z-mean)*rstd*gg.z + bb.z; o[3] = (v.w-mean)*rstd*gg.w + bb.w;
    ushort4 h4, l4;
    h4.x = f2bf(o[0]); l4.x = f2bf(o[0] - bf2f(h4.x));
    h4.y = f2bf(o[1]); l4.y = f2bf(o[1] - bf2f(h4.y));
    h4.z = f2bf(o[2]); l4.z = f2bf(o[2] - bf2f(h4.z));
    h4.w = f2bf(o[3]); l4.w = f2bf(o[3] - bf2f(h4.w));
    reinterpret_cast<ushort4*>(hi + (size_t)row * D_MODEL)[tid] = h4;
    reinterpret_cast<ushort4*>(lo + (size_t)row * D_MODEL)[tid] = l4;
}

// ----------------------------- MFMA GEMM ------------------------------------
// C[M,N](+epilogue) = A[M,K]bf16 @ B[N,K]bf16^T   (m97 structure, BM=128)
// BN in {128, 64}. KSPLIT: gridDim.z slices of length ksl; C += z*M*sC.
// Non-KSPLIT launches use XCD-aware bijective block swizzle (requires nwg%8==0).
// EP: 0 C=fp32 | 1 Cb=bf16 clip(v+bias) | 3 Cb=bf16 softplus(v+bias)
//     4 C=fp32 v+addx | 6 Cb=bf16 v | 7 C=fp32 v+bias+addx, absmax->gma
template<int EP, bool DUALA, int BN, bool KSPLIT>
__global__ __launch_bounds__(256) void mfma_gemm(
    const unsigned short* __restrict__ A, const unsigned short* __restrict__ A2,
    const unsigned short* __restrict__ B, float* __restrict__ C,
    unsigned short* __restrict__ Cb,
    int M, int N, int K, int sA, int sC,
    const float* __restrict__ bias, const float* __restrict__ addx, int sAdd,
    unsigned int* __restrict__ gma, int ksl)
{
    constexpr int NF = BN / 32;            // N-frags per wave (wave N-span BN/2)
    __shared__ __align__(16) unsigned short As[128*32];
    __shared__ __align__(16) unsigned short As2[DUALA ? 128*32 : 8];
    __shared__ __align__(16) unsigned short Bs[BN*32];
    __shared__ float redmax[4];
    const int tid = threadIdx.x;
    const int lane = tid & 63;
    const int w = tid >> 6;
    const int wm = w >> 1, wn = w & 1;

    int bx = blockIdx.x, by = blockIdx.y;
    if (!KSPLIT) {                          // XCD-aware bijective swizzle (nwg%8==0)
        const int gx = gridDim.x;
        const int nwg = gx * gridDim.y;
        int lin = by * gx + bx;
        int nl = (lin & 7) * (nwg >> 3) + (lin >> 3);
        bx = nl % gx; by = nl / gx;
    }
    const int row0 = by * 128, col0 = bx * BN;
    const int srow = lane >> 2;            // 0..15
    const int scol = (lane & 3) * 8;       // 0,8,16,24

    int k_begin = 0, k_end = K;
    if (KSPLIT) {
        int z = blockIdx.z;
        k_begin = z * ksl; k_end = k_begin + ksl;
        C += (size_t)z * M * sC;
    }

    f32x4 acc[4][NF];
    #pragma unroll
    for (int m = 0; m < 4; ++m)
        #pragma unroll
        for (int n = 0; n < NF; ++n)
            acc[m][n] = (f32x4){0.f, 0.f, 0.f, 0.f};

    for (int k0 = k_begin; k0 < k_end; k0 += 32) {
        #pragma unroll
        for (int i = 0; i < 2; ++i) {
            const int rbase = w * 32 + i * 16;               // wave-uniform
            stage16(A + (size_t)(row0 + rbase + srow) * sA + k0 + scol, &As[rbase * 32]);
            if (DUALA)
                stage16(A2 + (size_t)(row0 + rbase + srow) * sA + k0 + scol, &As2[rbase * 32]);
        }
        #pragma unroll
        for (int i = 0; i < BN/64; ++i) {
            const int rbase = (BN == 128) ? (w * 32 + i * 16) : (w * 16);
            if (col0 + rbase < N)                            // N%16==0 in all uses
                stage16(B + (size_t)(col0 + rbase + srow) * K + k0 + scol, &Bs[rbase * 32]);
        }
        __syncthreads();                                     // drains vmcnt before LDS reads

        short8v af[4], bfr[NF], af2[4];
        const int fr = lane & 15, kg = (lane >> 4) * 8;
        #pragma unroll
        for (int m = 0; m < 4; ++m)
            af[m] = *reinterpret_cast<const short8v*>(&As[(wm*64 + m*16 + fr) * 32 + kg]);
        if (DUALA) {
            #pragma unroll
            for (int m = 0; m < 4; ++m)
                af2[m] = *reinterpret_cast<const short8v*>(&As2[(wm*64 + m*16 + fr) * 32 + kg]);
        }
        #pragma unroll
        for (int n = 0; n < NF; ++n)
            bfr[n] = *reinterpret_cast<const short8v*>(&Bs[(wn*(BN/2) + n*16 + fr) * 32 + kg]);

        #pragma unroll
        for (int m = 0; m < 4; ++m)
            #pragma unroll
            for (int n = 0; n < NF; ++n) {
                acc[m][n] = __builtin_amdgcn_mfma_f32_16x16x32_bf16(af[m], bfr[n], acc[m][n], 0, 0, 0);
                if (DUALA)
                    acc[m][n] = __builtin_amdgcn_mfma_f32_16x16x32_bf16(af2[m], bfr[n], acc[m][n], 0, 0, 0);
            }
        __syncthreads();
    }

    // C/D layout (m89-verified): col = lane&15, row = (lane>>4)*4 + reg
    const int fc = lane & 15, r4 = (lane >> 4) * 4;
    float lmax = 0.0f;
    #pragma unroll
    for (int m = 0; m < 4; ++m) {
        const int grb = row0 + wm*64 + m*16 + r4;
        #pragma unroll
        for (int n = 0; n < NF; ++n) {
            const int gc = col0 + wn*(BN/2) + n*16 + fc;
            if (gc >= N) continue;
            #pragma unroll
            for (int j = 0; j < 4; ++j) {
                const int r = grb + j;
                float v = acc[m][n][j];
                if (EP == 0) {
                    C[(size_t)r*sC + gc] = v;
                } else if (EP == 1) {
                    v += bias[gc];
                    v = fminf(1.0f, fmaxf(-1.0f, v));
                    Cb[(size_t)r*sC + gc] = f2bf(v);
                } else if (EP == 3) {
                    float t = v + bias[gc];
                    t = fmaxf(t, 0.0f) + log1pf(__expf(-fabsf(t)));
                    Cb[(size_t)r*sC + gc] = f2bf(t);
                } else if (EP == 4) {
                    C[(size_t)r*sC + gc] = v + addx[(size_t)r*sAdd + gc];
                } else if (EP == 6) {
                    Cb[(size_t)r*sC + gc] = f2bf(v);
                } else { // EP == 7
                    v += bias[gc] + addx[(size_t)r*sAdd + gc];
                    C[(size_t)r*sC + gc] = v;
                    lmax = fmaxf(lmax, fabsf(v));
                }
            }
        }
    }
    if (EP == 7) {
        #pragma unroll
        for (int off = 32; off > 0; off >>= 1) lmax = fmaxf(lmax, __shfl_down(lmax, off));
        if (lane == 0) redmax[w] = lmax;
        __syncthreads();
        if (tid == 0) {
            float t = fmaxf(fmaxf(redmax[0], redmax[1]), fmaxf(redmax[2], redmax[3]));
            int g = (row0 & (SEQ - 1)) >> 9;   // 128-row tile lies in one 512-group
            atomicMax(gma + g, __float_as_uint(t));
        }
    }
}

// ------------- x_proj split-K combine: xdbl = sum partials; emit bf16 dt ----
__global__ __launch_bounds__(256) void xproj_combine_kernel(
    const float* __restrict__ part,     // [4][NTOK][96]
    float* __restrict__ xdbl,           // [NTOK][96]
    unsigned short* __restrict__ xdt)   // [NTOK][64]
{
    int i = blockIdx.x * 256 + threadIdx.x;          // f4 index, NTOK*24 total
    if (i >= NTOK * 24) return;
    const size_t stride = (size_t)NTOK * 96 / 4;
    float4 v0 = reinterpret_cast<const float4*>(part)[i];
    float4 v1 = reinterpret_cast<const float4*>(part)[i + stride];
    float4 v2 = reinterpret_cast<const float4*>(part)[i + 2*stride];
    float4 v3 = reinterpret_cast<const float4*>(part)[i + 3*stride];
    float4 o;
    o.x = (v0.x + v1.x) + (v2.x + v3.x);
    o.y = (v0.y + v1.y) + (v2.y + v3.y);
    o.z = (v0.z + v1.z) + (v2.z + v3.z);
    o.w = (v0.w + v1.w) + (v2.w + v3.w);
    reinterpret_cast<float4*>(xdbl)[i] = o;
    int row = i / 24, c4 = i % 24;
    if (c4 < 16) {                                    // cols 0..63 -> bf16 dt input
        ushort4 u;
        u.x = f2bf(o.x); u.y = f2bf(o.y); u.z = f2bf(o.z); u.w = f2bf(o.w);
        reinterpret_cast<ushort4*>(xdt + (size_t)row * 64)[c4] = u;
    }
}

// ------------------- fused quant + LN2 (qx fp32 + u bf16) -------------------
__global__ __launch_bounds__(256) void quant_ln_kernel(
    const float* __restrict__ x2, const unsigned int* __restrict__ gamma_bits,
    const float* __restrict__ g, const float* __restrict__ b,
    float* __restrict__ qx, unsigned short* __restrict__ u)
{
    int row = blockIdx.x, tid = threadIdx.x;
    int grp = (row & (SEQ - 1)) >> 9;
    float gamma = __uint_as_float(gamma_bits[grp]);
    float scale = 128.0f / (gamma + EPS);
    const float lo = -128.0f + EPS, hi = 128.0f - EPS;
    float4 v = reinterpret_cast<const float4*>(x2 + (size_t)row * D_MODEL)[tid];
    float4 qv;
    qv.x = fminf(hi, fmaxf(lo, v.x * scale));
    qv.y = fminf(hi, fmaxf(lo, v.y * scale));
    qv.z = fminf(hi, fmaxf(lo, v.z * scale));
    qv.w = fminf(hi, fmaxf(lo, v.w * scale));
    reinterpret_cast<float4*>(qx + (size_t)row * D_MODEL)[tid] = qv;
    float s = qv.x + qv.y + qv.z + qv.w;
    float q = qv.x*qv.x + qv.y*qv.y + qv.z*qv.z + qv.w*qv.w;
    #pragma unroll
    for (int off = 32; off > 0; off >>= 1) { s += __shfl_down(s, off); q += __shfl_down(q, off); }
    __shared__ float rs[4], rq[4], smean, srstd;
    if ((tid & 63) == 0) { rs[tid >> 6] = s; rq[tid >> 6] = q; }
    __syncthreads();
    if (tid == 0) {
        float ts = rs[0]+rs[1]+rs[2]+rs[3], tq = rq[0]+rq[1]+rq[2]+rq[3];
        float mean = ts * (1.0f / D_MODEL);
        smean = mean;
        srstd = rsqrtf(tq * (1.0f / D_MODEL) - mean*mean + EPS);
    }
    __syncthreads();
    float mean = smean, rstd = srstd;
    float4 gg = reinterpret_cast<const float4*>(g)[tid];
    float4 bb = reinterpret_cast<const float4*>(b)[tid];
    ushort4 o;
    o.x = f2bf((qv.x-mean)*rstd*gg.x + bb.x);
    o.y = f2bf((qv.y-mean)*rstd*gg.y + bb.y);
    o.z = f2bf((qv.z-mean)*rstd*gg.z + bb.z);
    o.w = f2bf((qv.w-mean)*rstd*gg.w + bb.w);
    reinterpret_cast<ushort4*>(u + (size_t)row * D_MODEL)[tid] = o;
}

// -------------- depthwise causal conv + SiLU (bf16 in/out) ------------------
__global__ __launch_bounds__(256) void conv_silu_kernel(const unsigned short* __restrict__ xz,
                                                        const float* __restrict__ conv_w,
                                                        const float* __restrict__ conv_b,
                                                        unsigned short* __restrict__ xcb) {
    int c = blockIdx.x * 256 + threadIdx.x;   // 0..2047
    int m = blockIdx.y;                        // 0..4095
    int b = m >> 11, l = m & (SEQ - 1);
    float4 w4 = reinterpret_cast<const float4*>(conv_w)[c];
    float wv[4] = {w4.x, w4.y, w4.z, w4.w};
    float s = conv_b[c];
    const unsigned short* base = xz + ((size_t)b * SEQ) * 4096 + c;
    #pragma unroll
    for (int k = 0; k < 4; ++k) {
        int ll = l - 3 + k;
        if (ll >= 0) s += bf2f(base[(size_t)ll * 4096]) * wv[k];
    }
    float sig = 1.0f / (1.0f + __expf(-s));
    xcb[(size_t)m * D_INNER + c] = f2bf(s * sig);
}

// ----------------------------- chunked selective scan ------------------------
__device__ __forceinline__ void make_dA(float dA[D_STATE], float dtv,
                                        const float* a, bool pw) {
    if (pw) {
        dA[0] = __expf(dtv * a[0]);
        #pragma unroll
        for (int s = 1; s < D_STATE; ++s) dA[s] = dA[s>>1] * dA[(s-1)>>1];
    } else {
        #pragma unroll
        for (int s = 0; s < D_STATE; ++s) dA[s] = __expf(dtv * a[s]);
    }
}

__global__ __launch_bounds__(256) void scan_partial_kernel(
    const unsigned short* __restrict__ dt, const unsigned short* __restrict__ xcb,
    const float* __restrict__ xdbl, const float* __restrict__ A_log,
    float* __restrict__ Lbuf, float* __restrict__ Sbuf)
{
    int gtid = blockIdx.x * 256 + threadIdx.x;
    int ch = gtid & (NCH - 1);
    int c  = gtid >> 12;                      // chunk 0..63
    int b = ch >> 11, d = ch & (D_INNER - 1);
    float a[D_STATE], h[D_STATE];
    bool pw = true;
    #pragma unroll
    for (int s = 0; s < D_STATE; ++s) {
        a[s] = -__expf(A_log[(size_t)d * D_STATE + s]);
        h[s] = 0.0f;
    }
    #pragma unroll
    for (int s = 1; s < D_STATE; ++s)
        pw = pw && (fabsf(a[s] - a[0]*(float)(s+1)) <= 1e-3f * fabsf(a[s]));

    size_t m0 = (size_t)b * SEQ + (size_t)c * CLEN;
    float Ssum = 0.0f;

    float dt_n = bf2f(dt[m0 * D_INNER + d]);
    float x_n  = bf2f(xcb[m0 * D_INNER + d]);
    float4 B_n[4];
    {
        const float* xd = xdbl + m0 * 96;
        #pragma unroll
        for (int i = 0; i < 4; ++i)
            B_n[i] = *reinterpret_cast<const float4*>(xd + DT_RANK + 4*i);
    }

    for (int l = 0; l < CLEN; ++l) {
        float dtv = dt_n, xv = x_n;
        float Bc[D_STATE];
        #pragma unroll
        for (int i = 0; i < 4; ++i) {
            Bc[4*i+0] = B_n[i].x; Bc[4*i+1] = B_n[i].y; Bc[4*i+2] = B_n[i].z; Bc[4*i+3] = B_n[i].w;
        }
        if (l + 1 < CLEN) {
            size_t m1 = m0 + l + 1;
            dt_n = bf2f(dt[m1 * D_INNER + d]);
            x_n  = bf2f(xcb[m1 * D_INNER + d]);
            const float* xd = xdbl + m1 * 96;
            #pragma unroll
            for (int i = 0; i < 4; ++i)
                B_n[i] = *reinterpret_cast<const float4*>(xd + DT_RANK + 4*i);
        }
        Ssum += dtv;
        float dx = dtv * xv;
        float dA[D_STATE];
        make_dA(dA, dtv, a, pw);
        #pragma unroll
        for (int s = 0; s < D_STATE; ++s)
            h[s] = h[s] * dA[s] + dx * Bc[s];
    }
    float4* Lp = reinterpret_cast<float4*>(Lbuf + (size_t)c * (NCH * D_STATE) + (size_t)ch * D_STATE);
    Lp[0] = make_float4(h[0], h[1], h[2], h[3]);
    Lp[1] = make_float4(h[4], h[5], h[6], h[7]);
    Lp[2] = make_float4(h[8], h[9], h[10], h[11]);
    Lp[3] = make_float4(h[12], h[13], h[14], h[15]);
    Sbuf[(size_t)c * NCH + ch] = Ssum;
}

__global__ __launch_bounds__(256) void scan_combine_kernel(
    float* __restrict__ LH, const float* __restrict__ Sbuf,
    const float* __restrict__ A_log)
{
    int gtid = blockIdx.x * 256 + threadIdx.x;
    int s = gtid & (D_STATE - 1);
    int ch = gtid >> 4;
    int d = ch & (D_INNER - 1);
    float a = -__expf(A_log[(size_t)d * D_STATE + s]);
    float h = 0.0f;
    #pragma unroll 4
    for (int c = 0; c < NCHUNK; ++c) {
        size_t idx = (size_t)c * (NCH * D_STATE) + (size_t)ch * D_STATE + s;
        float loc = LH[idx];
        LH[idx] = h;
        float P = __expf(a * Sbuf[(size_t)c * NCH + ch]);
        h = h * P + loc;
    }
}

__global__ __launch_bounds__(256) void scan_final_kernel(
    const unsigned short* __restrict__ dt, const unsigned short* __restrict__ xcb,
    const unsigned short* __restrict__ xzb, const float* __restrict__ xdbl,
    const float* __restrict__ A_log, const float* __restrict__ D_param,
    const float* __restrict__ Hin, unsigned short* __restrict__ yb)
{
    int gtid = blockIdx.x * 256 + threadIdx.x;
    int ch = gtid & (NCH - 1);
    int c  = gtid >> 12;
    int b = ch >> 11, d = ch & (D_INNER - 1);
    float a[D_STATE], h[D_STATE];
    {
        const float4* Hp = reinterpret_cast<const float4*>(
            Hin + (size_t)c * (NCH * D_STATE) + (size_t)ch * D_STATE);
        float4 h0 = Hp[0], h1 = Hp[1], h2 = Hp[2], h3 = Hp[3];
        h[0]=h0.x; h[1]=h0.y; h[2]=h0.z; h[3]=h0.w;
        h[4]=h1.x; h[5]=h1.y; h[6]=h1.z; h[7]=h1.w;
        h[8]=h2.x; h[9]=h2.y; h[10]=h2.z; h[11]=h2.w;
        h[12]=h3.x; h[13]=h3.y; h[14]=h3.z; h[15]=h3.w;
    }
    bool pw = true;
    #pragma unroll
    for (int s = 0; s < D_STATE; ++s)
        a[s] = -__expf(A_log[(size_t)d * D_STATE + s]);
    #pragma unroll
    for (int s = 1; s < D_STATE; ++s)
        pw = pw && (fabsf(a[s] - a[0]*(float)(s+1)) <= 1e-3f * fabsf(a[s]));
    float Dp = D_param[d];

    size_t m0 = (size_t)b * SEQ + (size_t)c * CLEN;
    float dt_n = bf2f(dt[m0 * D_INNER + d]);
    float x_n  = bf2f(xcb[m0 * D_INNER + d]);
    float z_n  = bf2f(xzb[m0 * 4096 + D_INNER + d]);
    float4 B_n[4], C_n[4];
    {
        const float* xd = xdbl + m0 * 96;
        #pragma unroll
        for (int i = 0; i < 4; ++i) {
            B_n[i] = *reinterpret_cast<const float4*>(xd + DT_RANK + 4*i);
            C_n[i] = *reinterpret_cast<const float4*>(xd + DT_RANK + D_STATE + 4*i);
        }
    }

    for (int l = 0; l < CLEN; ++l) {
        float dtv = dt_n, xv = x_n, zv = z_n;
        float Bc[D_STATE], Cc[D_STATE];
        #pragma unroll
        for (int i = 0; i < 4; ++i) {
            Bc[4*i+0] = B_n[i].x; Bc[4*i+1] = B_n[i].y; Bc[4*i+2] = B_n[i].z; Bc[4*i+3] = B_n[i].w;
            Cc[4*i+0] = C_n[i].x; Cc[4*i+1] = C_n[i].y; Cc[4*i+2] = C_n[i].z; Cc[4*i+3] = C_n[i].w;
        }
        if (l + 1 < CLEN) {
            size_t m1 = m0 + l + 1;
            dt_n = bf2f(dt[m1 * D_INNER + d]);
            x_n  = bf2f(xcb[m1 * D_INNER + d]);
            z_n  = bf2f(xzb[m1 * 4096 + D_INNER + d]);
            const float* xd = xdbl + m1 * 96;
            #pragma unroll
            for (int i = 0; i < 4; ++i) {
                B_n[i] = *reinterpret_cast<const float4*>(xd + DT_RANK + 4*i);
                C_n[i] = *reinterpret_cast<const float4*>(xd + DT_RANK + D_STATE + 4*i);
            }
        }
        float dx = dtv * xv;
        float yv = 0.0f;
        float dA[D_STATE];
        make_dA(dA, dtv, a, pw);
        #pragma unroll
        for (int s = 0; s < D_STATE; ++s) {
            h[s] = h[s] * dA[s] + dx * Bc[s];
            yv += h[s] * Cc[s];
        }
        yv += Dp * xv;
        float sig = 1.0f / (1.0f + __expf(-zv));
        yb[(m0 + l) * D_INNER + d] = f2bf(yv * (zv * sig));
    }
}

// ----------------------------- launch ---------------------------------------
extern "C" void kernel_launch(void* const* d_in, const int* in_sizes, int n_in,
                              void* d_out, int out_size, void* d_ws, size_t ws_size,
                              hipStream_t stream) {
    const float* x         = (const float*)d_in[0];
    const float* ln1_g     = (const float*)d_in[1];
    const float* ln1_b     = (const float*)d_in[2];
    const float* ln2_g     = (const float*)d_in[3];
    const float* ln2_b     = (const float*)d_in[4];
    const float* W1        = (const float*)d_in[5];
    const float* b1        = (const float*)d_in[6];
    const float* W2        = (const float*)d_in[7];
    const float* b2        = (const float*)d_in[8];
    const float* in_proj   = (const float*)d_in[9];
    const float* conv_w    = (const float*)d_in[10];
    const float* conv_b    = (const float*)d_in[11];
    const float* x_proj    = (const float*)d_in[12];
    const float* dt_proj   = (const float*)d_in[13];
    const float* dt_proj_b = (const float*)d_in[14];
    const float* A_log     = (const float*)d_in[15];
    const float* D_param   = (const float*)d_in[16];
    const float* out_proj  = (const float*)d_in[17];
    float* out = (float*)d_out;

    // ---- workspace layout (bytes), ~159 MiB ----
    char* ws = (char*)d_ws;
    float*          f_x2   = (float*)         (ws + 0);          // 16,777,216  x2/qx
    unsigned short* b_xz   = (unsigned short*)(ws + 16777216);   // 33,554,432  bf16 [xs|z]
    unsigned short* b_dt   = (unsigned short*)(ws + 50331648);   // 16,777,216  dt bf16
    float*          f_xdbl = (float*)         (ws + 83886080);   //  1,572,864
    float*          f_L    = (float*)         (ws + 85458944);   // 16,777,216  (scan L; earlier: xproj partials)
    float*          f_xp   = f_L;                                //  6,291,456  alias (consumed before scan)
    float*          f_S    = (float*)         (ws + 102236160);  //  1,048,576
    unsigned int*   f_gamma= (unsigned int*)  (ws + 103284736);  // 64
    unsigned short* b_a1hi = (unsigned short*)(ws + 103284800);  //  8,388,608
    unsigned short* b_a1lo = b_a1hi + 4194304;                   //  8,388,608
    unsigned short* b_y    = b_a1hi;                             //  reuse 16 MB
    unsigned short* b_gated= (unsigned short*)(ws + 120062016);  // 16,777,216
    unsigned short* b_xc   = b_gated;                            //  reuse
    unsigned short* b_u    = (unsigned short*)(ws + 136839232);  //  8,388,608
    unsigned short* b_xdt  = b_u;                                //  reuse 512 KB
    unsigned short* b_w1s  = (unsigned short*)(ws + 145227840);  //  4,194,304
    unsigned short* b_w2s  = (unsigned short*)(ws + 149422144);  //  4,194,304
    unsigned short* b_inpj = (unsigned short*)(ws + 153616448);  //  8,388,608
    unsigned short* b_xpj  = (unsigned short*)(ws + 162005056);  //    393,216
    unsigned short* b_dtpj = (unsigned short*)(ws + 162398272);  //    262,144
    unsigned short* b_outpj= (unsigned short*)(ws + 162660416);  //  4,194,304

    dim3 b256(256);

    // 0. all weight conversions (+ gamma init) in one launch
    f2bf_all_kernel<<<dim3((F4_C6 + 255)/256), b256, 0, stream>>>(
        W1, W2, in_proj, x_proj, dt_proj, out_proj,
        b_w1s, b_w2s, b_inpj, b_xpj, b_dtpj, b_outpj, f_gamma);

    // 1. LN1 -> hi/lo bf16
    ln_hilo_kernel<<<dim3(NTOK), b256, 0, stream>>>(x, ln1_g, ln1_b, b_a1hi, b_a1lo);
    // 2. gated = clip((hi+lo) @ sign(W1)^T + b1) -> bf16   [BN=128, 512 blocks]
    mfma_gemm<1, true, 128, false><<<dim3(16, 32), b256, 0, stream>>>(
        b_a1hi, b_a1lo, b_w1s, nullptr, b_gated, NTOK, D_INNER, D_MODEL, D_MODEL, D_INNER,
        b1, nullptr, 0, nullptr, 0);
    // 3. x2 = gated @ sign(W2)^T + b2 + x -> fp32, fused absmax [BN=128, 256 blocks]
    mfma_gemm<7, false, 128, false><<<dim3(8, 32), b256, 0, stream>>>(
        b_gated, nullptr, b_w2s, f_x2, nullptr, NTOK, D_MODEL, D_INNER, D_INNER, D_MODEL,
        b2, x, D_MODEL, f_gamma, 0);
    // 4+5. fused quant + LN2 -> qx fp32, u bf16
    quant_ln_kernel<<<dim3(NTOK), b256, 0, stream>>>(f_x2, f_gamma, ln2_g, ln2_b, f_x2, b_u);
    // 6. xz = u @ in_proj^T -> bf16   [BN=128, 1024 blocks]
    mfma_gemm<6, false, 128, false><<<dim3(32, 32), b256, 0, stream>>>(
        b_u, nullptr, b_inpj, nullptr, b_xz, NTOK, 2*D_INNER, D_MODEL, D_MODEL, 2*D_INNER,
        nullptr, nullptr, 0, nullptr, 0);
    // 7. conv + silu -> bf16 xc
    conv_silu_kernel<<<dim3(D_INNER/256, NTOK), b256, 0, stream>>>(b_xz, conv_w, conv_b, b_xc);
    // 8. x_dbl partials = xc @ x_proj^T  [split-K x4, 128 blocks]
    mfma_gemm<0, false, 128, true><<<dim3(1, 32, 4), b256, 0, stream>>>(
        b_xc, nullptr, b_xpj, f_xp, nullptr, NTOK, DT_RANK + 2*D_STATE, D_INNER, D_INNER,
        DT_RANK + 2*D_STATE, nullptr, nullptr, 0, nullptr, 512);
    // 8b. combine partials -> f_xdbl fp32 + b_xdt bf16
    xproj_combine_kernel<<<dim3((NTOK*24 + 255)/256), b256, 0, stream>>>(f_xp, f_xdbl, b_xdt);
    // 9. dt = softplus(xdt @ dt_proj^T + b) -> bf16  [BN=64, 1024 blocks]
    mfma_gemm<3, false, 64, false><<<dim3(32, 32), b256, 0, stream>>>(
        b_xdt, nullptr, b_dtpj, nullptr, b_dt, NTOK, D_INNER, DT_RANK, DT_RANK, D_INNER,
        dt_proj_b, nullptr, 0, nullptr, 0);
    // 10. chunked scan
    scan_partial_kernel<<<dim3(NCH*NCHUNK/256), b256, 0, stream>>>(
        b_dt, b_xc, f_xdbl, A_log, f_L, f_S);
    scan_combine_kernel<<<dim3(NCH*D_STATE/256), b256, 0, stream>>>(f_L, f_S, A_log);
    scan_final_kernel<<<dim3(NCH*NCHUNK/256), b256, 0, stream>>>(
        b_dt, b_xc, b_xz, f_xdbl, A_log, D_param, f_L, b_y);
    // 11. out = y @ out_proj^T + qx -> fp32  [BN=128, 256 blocks]
    mfma_gemm<4, false, 128, false><<<dim3(8, 32), b256, 0, stream>>>(
        b_y, nullptr, b_outpj, out, nullptr, NTOK, D_MODEL, D_INNER, D_INNER, D_MODEL,
        nullptr, f_x2, D_MODEL, nullptr, 0);
}